// Round 11
// baseline (720.223 us; speedup 1.0000x reference)
//
#include <hip/hip_runtime.h>
#include <hip/hip_bf16.h>
#include <cstdint>

#define T_DIM 2048
#define C_DIM 256
#define BS 8
#define NPTS (BS * T_DIM)
#define KNB 10
#define NCH 16   // candidate chunks of 128

typedef __bf16 bf16x8 __attribute__((ext_vector_type(8)));
typedef float f32x4 __attribute__((ext_vector_type(4)));
typedef unsigned long long u64;

#define AS1 __attribute__((address_space(1)))
#define AS3 __attribute__((address_space(3)))

__device__ __forceinline__ unsigned short f2bf_rn(float f) {
  unsigned u = __float_as_uint(f);
  unsigned r = (u + 0x7FFFu + ((u >> 16) & 1u)) >> 16;
  return (unsigned short)r;
}
__device__ __forceinline__ float bfbits2f(unsigned short h) {
  return __uint_as_float((unsigned)h << 16);
}
__device__ __forceinline__ __bf16 bfbits(unsigned short h) {
  return __builtin_bit_cast(__bf16, h);
}

// pinned dif computation: identical instruction sequence at every use site.
__device__ __forceinline__ unsigned key_hi(float sqi, float sqj, float gv) {
  float dif = __fmaf_rn(-2.0f, gv, __fadd_rn(sqi, sqj));
  unsigned u = __float_as_uint(dif);
  return (u & 0x80000000u) ? ~u : (u | 0x80000000u);
}

// ---- stage a 128x64 bf16 tile into XOR-swizzled LDS via global_load_lds ----
__device__ __forceinline__ void stage_tile(const __bf16* __restrict__ src, size_t row0,
                                           int ld, int k0, __bf16* lds, int w, int l) {
  int kofs = ((l & 7) ^ (l >> 3)) * 8;
  const __bf16* g0 = src + (row0 + (size_t)(l >> 3)) * ld + k0 + kofs;
  __bf16* lbase = lds + (size_t)(w * 4) * 512;
#pragma unroll
  for (int q4 = 0; q4 < 4; ++q4) {
    __builtin_amdgcn_global_load_lds((AS1 void*)(g0 + (size_t)(w * 4 + q4) * 8 * ld),
                                     (AS3 void*)(lbase + q4 * 512), 16, 0, 0);
  }
}

// ---- stage a 64x64 bf16 tile (row panel) ----
__device__ __forceinline__ void stage_tile64(const __bf16* __restrict__ src, size_t row0,
                                             int k0, __bf16* lds, int w, int l) {
  int kofs = ((l & 7) ^ (l >> 3)) * 8;
  const __bf16* g0 = src + (row0 + (size_t)(l >> 3)) * C_DIM + k0 + kofs;
  __bf16* lbase = lds + (size_t)(w * 2) * 512;
#pragma unroll
  for (int q4 = 0; q4 < 2; ++q4) {
    __builtin_amdgcn_global_load_lds((AS1 void*)(g0 + (size_t)(w * 2 + q4) * 8 * C_DIM),
                                     (AS3 void*)(lbase + q4 * 512), 16, 0, 0);
  }
}

// conv im2col staging: K=768 = 3 taps x 256
__device__ __forceinline__ void stage_tile_conv(const __bf16* __restrict__ src, int m0,
                                                int k0in, const __bf16* __restrict__ zp,
                                                __bf16* lds, int w, int l) {
  int tap = k0in >> 8;
  int kshift = tap - 1;
  int k0 = k0in & 255;
  int kofs = ((l & 7) ^ (l >> 3)) * 8;
  int mb = m0 & (T_DIM - 1);
#pragma unroll
  for (int q4 = 0; q4 < 4; ++q4) {
    int q = w * 4 + q4;
    int row = q * 8 + (l >> 3);
    int t = mb + row + kshift;
    const __bf16* g = ((unsigned)t < (unsigned)T_DIM)
                          ? (src + (size_t)(m0 + row + kshift) * C_DIM + k0 + kofs)
                          : (zp + kofs);
    __builtin_amdgcn_global_load_lds((AS1 void*)g, (AS3 void*)(lds + q * 512), 16, 0, 0);
  }
}

__device__ __forceinline__ bf16x8 read_frag(const __bf16* lds, int t16, int ks, int l) {
  int row = t16 * 16 + (l & 15);
  int kb = ks * 64 + ((l >> 4) << 4);
  int byte = row * 128 + (kb ^ ((row & 7) << 4));
  return *(const bf16x8*)((const char*)lds + byte);
}

// ---------------- transpose + hi/lo bf16 split ----------------
__global__ __launch_bounds__(256) void k_transpose_split(const float* __restrict__ x,
                                                         __bf16* __restrict__ Fh,
                                                         __bf16* __restrict__ Fl) {
  __shared__ float tile[32][33];
  int b = blockIdx.z;
  int t0 = blockIdx.x * 32;
  int c0 = blockIdx.y * 32;
  int tx = threadIdx.x & 31, ty = threadIdx.x >> 5;
  const float* xb = x + (size_t)b * C_DIM * T_DIM;
#pragma unroll
  for (int r = 0; r < 4; ++r) {
    int c = c0 + ty + 8 * r;
    tile[ty + 8 * r][tx] = xb[(size_t)c * T_DIM + t0 + tx];
  }
  __syncthreads();
#pragma unroll
  for (int r = 0; r < 4; ++r) {
    int t = t0 + ty + 8 * r;
    float v = tile[tx][ty + 8 * r];
    unsigned short hb = f2bf_rn(v);
    float lo = v - bfbits2f(hb);
    size_t o = ((size_t)b * T_DIM + t) * C_DIM + c0 + tx;
    Fh[o] = bfbits(hb);
    Fl[o] = bfbits(f2bf_rn(lo));
  }
}

// ---------------- sq[n] = sum_c (hi+lo)^2 ----------------
__global__ __launch_bounds__(256) void k_sq(const __bf16* __restrict__ Fh,
                                            const __bf16* __restrict__ Fl,
                                            float* __restrict__ sq) {
  int n = blockIdx.x * 4 + (threadIdx.x >> 6);
  int lane = threadIdx.x & 63;
  ushort4 hv = ((const ushort4*)Fh)[(size_t)n * 64 + lane];
  ushort4 lv = ((const ushort4*)Fl)[(size_t)n * 64 + lane];
  float s = 0.f;
  {
    float v;
    v = bfbits2f(hv.x) + bfbits2f(lv.x); s = fmaf(v, v, s);
    v = bfbits2f(hv.y) + bfbits2f(lv.y); s = fmaf(v, v, s);
    v = bfbits2f(hv.z) + bfbits2f(lv.z); s = fmaf(v, v, s);
    v = bfbits2f(hv.w) + bfbits2f(lv.w); s = fmaf(v, v, s);
  }
#pragma unroll
  for (int d = 1; d < 64; d <<= 1) s += __shfl_xor(s, d, 64);
  if (lane == 0) sq[n] = s;
}

// ---------------- gram tile + per-lane min-3 reduce (gram never hits HBM) ----------------
// Block = (chunk of 128 cands) x (panel of 64 rows) x batch. Swapped MFMA (cand=A,
// row=B) => lane l of wave w serves row w*16+(l&15); its cands = j*16+(l>>4)*4+r.
// Pass order per k identical to R10 (verified): candhi*rowhi, candhi*rowlo, candlo*rowhi.
// Epilogue: exact per-lane min-3 of its 32 keys; write min-2 (kept) + per-(row,chunk)
// min-over-quarters of 3rd (exclusion bound).
__global__ __launch_bounds__(256) void k_gram_reduce(const __bf16* __restrict__ Fh,
                                                     const __bf16* __restrict__ Fl,
                                                     const float* __restrict__ sq,
                                                     u64* __restrict__ kbuf,
                                                     u64* __restrict__ bbuf) {
  __shared__ __bf16 Bh[128 * 64], Bl[128 * 64];   // cand tiles (hi/lo)
  __shared__ __bf16 Rh[64 * 64], Rl[64 * 64];     // row tiles (hi/lo)
  __shared__ float sqc[128];

  int ch = blockIdx.x, p = blockIdx.y, b = blockIdx.z;
  size_t base = (size_t)b * T_DIM;
  const float* sqb = sq + base;
  int tid = threadIdx.x, w = tid >> 6, l = tid & 63, g = l >> 4;
  int r0 = p * 64;
  int cand0 = ch * 128;
  int myrow = r0 + w * 16 + (l & 15);
  float sqi = sqb[myrow];
  if (tid < 128) sqc[tid] = sqb[cand0 + tid];

  f32x4 acc[8];
#pragma unroll
  for (int j = 0; j < 8; ++j) acc[j] = {0.f, 0.f, 0.f, 0.f};

  for (int k0 = 0; k0 < C_DIM; k0 += 64) {
    stage_tile(Fh, base + cand0, C_DIM, k0, Bh, w, l);
    stage_tile(Fl, base + cand0, C_DIM, k0, Bl, w, l);
    stage_tile64(Fh, base + r0, k0, Rh, w, l);
    stage_tile64(Fl, base + r0, k0, Rl, w, l);
    __syncthreads();
#pragma unroll
    for (int ks = 0; ks < 2; ++ks) {
      bf16x8 rh = read_frag(Rh, w, ks, l);
      bf16x8 rl = read_frag(Rl, w, ks, l);
      bf16x8 cv[8];
#pragma unroll
      for (int j = 0; j < 8; ++j) cv[j] = read_frag(Bh, j, ks, l);
#pragma unroll
      for (int j = 0; j < 8; ++j)
        acc[j] = __builtin_amdgcn_mfma_f32_16x16x32_bf16(cv[j], rh, acc[j], 0, 0, 0);
#pragma unroll
      for (int j = 0; j < 8; ++j)
        acc[j] = __builtin_amdgcn_mfma_f32_16x16x32_bf16(cv[j], rl, acc[j], 0, 0, 0);
#pragma unroll
      for (int j = 0; j < 8; ++j) cv[j] = read_frag(Bl, j, ks, l);
#pragma unroll
      for (int j = 0; j < 8; ++j)
        acc[j] = __builtin_amdgcn_mfma_f32_16x16x32_bf16(cv[j], rh, acc[j], 0, 0, 0);
    }
    __syncthreads();
  }

  // exact per-lane min-3 over this lane's 32 scores
  u64 c0 = ~0ull, c1 = ~0ull, c2 = ~0ull;
#pragma unroll
  for (int j = 0; j < 8; ++j) {
    f32x4 sv = *(const f32x4*)&sqc[j * 16 + (g << 2)];
#pragma unroll
    for (int r = 0; r < 4; ++r) {
      unsigned u = key_hi(sqi, sv[r], acc[j][r]);
      u64 key = ((u64)u << 32) | (unsigned)(cand0 + j * 16 + (g << 2) + r);
      u64 t1 = (key > c0) ? key : c0; c0 = (key < c0) ? key : c0;
      u64 t2 = (t1 > c1) ? t1 : c1;  c1 = (t1 < c1) ? t1 : c1;
      c2 = (t2 < c2) ? t2 : c2;
    }
  }
  // keys: kbuf[((b*NCH + ch)*T_DIM + row)*8 + g*2 .. +1]  (coalesced 1KB per wave)
  u64* kp = kbuf + ((((size_t)b * NCH + ch) * T_DIM + myrow) * 8 + g * 2);
  kp[0] = c0;
  kp[1] = c1;
  // bound: min over quarters of the 3rd-smallest
  u64 bd = c2;
  { u64 o = __shfl_xor(bd, 16, 64); bd = (o < bd) ? o : bd; }
  { u64 o = __shfl_xor(bd, 32, 64); bd = (o < bd) ? o : bd; }
  if (g == 0) bbuf[((size_t)b * NCH + ch) * T_DIM + myrow] = bd;
}

// ---------------- merge: 128 kept keys/row -> top-10 + theta + flag ----------------
__global__ __launch_bounds__(256) void k_topk_merge(const u64* __restrict__ kbuf,
                                                    const u64* __restrict__ bbuf,
                                                    const float* __restrict__ sq,
                                                    int* __restrict__ idxo,
                                                    float* __restrict__ wo,
                                                    int* __restrict__ fixlist,
                                                    int* __restrict__ fixcount) {
  int b = blockIdx.y;
  int row = blockIdx.x * 4 + (threadIdx.x >> 6);
  int lane = threadIdx.x & 63;
  const float* sqb = sq + (size_t)b * T_DIM;
  float sqi = sqb[row];

  // lane covers (chunk = lane>>2, quarter = lane&3): its kept min-2
  const u64* kp = kbuf + ((((size_t)b * NCH + (lane >> 2)) * T_DIM + row) * 8 + (lane & 3) * 2);
  u64 m0 = kp[0], m1 = kp[1];
  u64 excl = (lane < NCH) ? bbuf[((size_t)b * NCH + lane) * T_DIM + row] : ~0ull;

  // 10-round extract-min (u32 hi butterfly, then lo among hi-matching)
  u64 win[KNB];
#pragma unroll
  for (int s = 0; s < KNB; ++s) {
    unsigned mh = (unsigned)(m0 >> 32);
    unsigned h = mh;
#pragma unroll
    for (int d = 1; d < 64; d <<= 1) {
      unsigned oh = __shfl_xor(h, d, 64);
      h = (oh < h) ? oh : h;
    }
    unsigned lo = (mh == h) ? (unsigned)m0 : 0xFFFFFFFFu;
#pragma unroll
    for (int d = 1; d < 64; d <<= 1) {
      unsigned ol = __shfl_xor(lo, d, 64);
      lo = (ol < lo) ? ol : lo;
    }
    u64 m = ((u64)h << 32) | lo;
    win[s] = m;
    bool pop = (m0 == m);
    m0 = pop ? m1 : m0;
    m1 = pop ? ~0ull : m1;
  }
  u64 theta = win[KNB - 1];

  // parallel epilogue: lane s writes winner s (output order-invariant: max over k)
  u64 mywin = win[0];
#pragma unroll
  for (int s = 1; s < KNB; ++s) mywin = (lane == s) ? win[s] : mywin;
  if (lane < KNB) {
    int j = (int)(unsigned)(mywin & 0xffffffffull);
    unsigned su = (unsigned)(mywin >> 32);
    unsigned bits = (su & 0x80000000u) ? (su & 0x7fffffffu) : ~su;
    float dif = __uint_as_float(bits);
    float sqj = sqb[j];
    float num = 0.5f * (sqi + sqj - dif);
    float wv = num / (sqrtf(sqi) * sqrtf(sqj));
    idxo[((size_t)b * T_DIM + row) * KNB + lane] = j;
    wo[((size_t)b * T_DIM + row) * KNB + lane] = wv;
  }

  // flag iff smallest excluded bound < theta
#pragma unroll
  for (int d = 1; d < 64; d <<= 1) {
    u64 o = __shfl_xor(excl, d, 64);
    excl = (o < excl) ? o : excl;
  }
  if (lane == 0 && excl < theta) {
    int slot = atomicAdd(fixcount, 1);
    fixlist[slot] = (int)(b * T_DIM + row);
  }
}

// ---------------- FIX kernel: recompute flagged rows exactly (fp32 VALU) ----------------
__global__ __launch_bounds__(256) void k_topk_fix(const __bf16* __restrict__ Fh,
                                                  const __bf16* __restrict__ Fl,
                                                  const float* __restrict__ sq,
                                                  const int* __restrict__ fixlist,
                                                  const int* __restrict__ fixcount,
                                                  int* __restrict__ idxo,
                                                  float* __restrict__ wo) {
  __shared__ float xr[C_DIM];
  __shared__ float difs[T_DIM];
  int n = fixcount[0];
  int tid = threadIdx.x;
  for (int i = blockIdx.x; i < n; i += gridDim.x) {
    int rowg = fixlist[i];
    int b = rowg >> 11, r = rowg & (T_DIM - 1);
    const unsigned short* fh = (const unsigned short*)Fh;
    const unsigned short* fl = (const unsigned short*)Fl;
    xr[tid] = bfbits2f(fh[(size_t)rowg * C_DIM + tid]) + bfbits2f(fl[(size_t)rowg * C_DIM + tid]);
    __syncthreads();
    const float* sqb = sq + (size_t)b * T_DIM;
    float sqi = sqb[r];
#pragma unroll 2
    for (int it = 0; it < 8; ++it) {
      int j = tid + it * 256;
      const ushort4* chp = (const ushort4*)(fh + ((size_t)b * T_DIM + j) * C_DIM);
      const ushort4* clp = (const ushort4*)(fl + ((size_t)b * T_DIM + j) * C_DIM);
      float dot = 0.f;
      for (int c4 = 0; c4 < 64; ++c4) {
        ushort4 h = chp[c4];
        ushort4 lo = clp[c4];
        dot = fmaf(bfbits2f(h.x) + bfbits2f(lo.x), xr[c4 * 4 + 0], dot);
        dot = fmaf(bfbits2f(h.y) + bfbits2f(lo.y), xr[c4 * 4 + 1], dot);
        dot = fmaf(bfbits2f(h.z) + bfbits2f(lo.z), xr[c4 * 4 + 2], dot);
        dot = fmaf(bfbits2f(h.w) + bfbits2f(lo.w), xr[c4 * 4 + 3], dot);
      }
      difs[j] = __fmaf_rn(-2.0f, dot, __fadd_rn(sqi, sqb[j]));
    }
    __syncthreads();
    if (tid < 64) {
      int lane = tid;
      u64 b0 = ~0ull, b1 = ~0ull, b2 = ~0ull, b3 = ~0ull, b4 = ~0ull,
          b5 = ~0ull, b6 = ~0ull, b7 = ~0ull, b8 = ~0ull, b9 = ~0ull;
      for (int t = 0; t < 32; ++t) {
        unsigned j = (unsigned)(lane + 64 * t);
        unsigned u = __float_as_uint(difs[j]);
        u = (u & 0x80000000u) ? ~u : (u | 0x80000000u);
        u64 key = ((u64)u << 32) | j;
        if (key < b9) {
          b9 = key;
          u64 tt;
          if (b9 < b8) { tt = b8; b8 = b9; b9 = tt; }
          if (b8 < b7) { tt = b7; b7 = b8; b8 = tt; }
          if (b7 < b6) { tt = b6; b6 = b7; b7 = tt; }
          if (b6 < b5) { tt = b5; b5 = b6; b6 = tt; }
          if (b5 < b4) { tt = b4; b4 = b5; b5 = tt; }
          if (b4 < b3) { tt = b3; b3 = b4; b4 = tt; }
          if (b3 < b2) { tt = b2; b2 = b3; b3 = tt; }
          if (b2 < b1) { tt = b1; b1 = b2; b2 = tt; }
          if (b1 < b0) { tt = b0; b0 = b1; b1 = tt; }
        }
      }
      int* idxb = idxo + (size_t)b * T_DIM * KNB;
      float* wbp = wo + (size_t)b * T_DIM * KNB;
#pragma unroll
      for (int s = 0; s < KNB; ++s) {
        u64 m = b0;
#pragma unroll
        for (int d = 1; d < 64; d <<= 1) {
          u64 o = __shfl_xor(m, d, 64);
          m = (o < m) ? o : m;
        }
        u64 bal = __ballot(b0 == m);
        int leader = (int)__builtin_ctzll(bal);
        if (lane == leader) {
          b0 = b1; b1 = b2; b2 = b3; b3 = b4; b4 = b5;
          b5 = b6; b6 = b7; b7 = b8; b8 = b9; b9 = ~0ull;
        }
        if (lane == 0) {
          int j = (int)(unsigned)(m & 0xffffffffull);
          unsigned su = (unsigned)(m >> 32);
          unsigned bits = (su & 0x80000000u) ? (su & 0x7fffffffu) : ~su;
          float dif = __uint_as_float(bits);
          float sqj = sqb[j];
          float num = 0.5f * (sqi + sqj - dif);
          float wv = num / (sqrtf(sqi) * sqrtf(sqj));
          idxb[(size_t)r * KNB + s] = j;
          wbp[(size_t)r * KNB + s] = wv;
        }
      }
    }
    __syncthreads();
  }
}

// ---------------- merged bf16 GEMM dispatch: blocks 0-3 MLP, 4-5 conv ----------------
__global__ __launch_bounds__(256, 2) void k_gemm_fused(const __bf16* __restrict__ Fh,
                                                       const __bf16* __restrict__ mlpB,
                                                       const __bf16* __restrict__ wk3,
                                                       float* __restrict__ mlpout,
                                                       float* __restrict__ convout,
                                                       const __bf16* __restrict__ zp) {
  __shared__ __bf16 As[128 * 64], Bs[128 * 64];
  int bx = blockIdx.x;
  const __bf16* Bm;
  float* C;
  int N, K, conv, n0;
  if (bx < 4) {
    Bm = mlpB; C = mlpout; N = 512; K = 256; conv = 0; n0 = bx * 128;
  } else {
    Bm = wk3; C = convout; N = 256; K = 768; conv = 1; n0 = (bx - 4) * 128;
  }
  int m0 = blockIdx.y * 128;
  int tid = threadIdx.x, w = tid >> 6, l = tid & 63;
  int wr = w >> 1, wc = w & 1;
  f32x4 acc[4][4];
#pragma unroll
  for (int i = 0; i < 4; ++i)
#pragma unroll
    for (int j = 0; j < 4; ++j) acc[i][j] = {0.f, 0.f, 0.f, 0.f};

  for (int k0 = 0; k0 < K; k0 += 64) {
    if (conv)
      stage_tile_conv(Fh, m0, k0, zp, As, w, l);
    else
      stage_tile(Fh, (size_t)m0, C_DIM, k0, As, w, l);
    stage_tile(Bm, (size_t)n0, K, k0, Bs, w, l);
    __syncthreads();
#pragma unroll
    for (int ks = 0; ks < 2; ++ks) {
      bf16x8 af[4], bf_[4];
#pragma unroll
      for (int i = 0; i < 4; ++i) af[i] = read_frag(As, wr * 4 + i, ks, l);
#pragma unroll
      for (int j = 0; j < 4; ++j) bf_[j] = read_frag(Bs, wc * 4 + j, ks, l);
#pragma unroll
      for (int i = 0; i < 4; ++i)
#pragma unroll
        for (int j = 0; j < 4; ++j)
          acc[i][j] = __builtin_amdgcn_mfma_f32_16x16x32_bf16(af[i], bf_[j], acc[i][j], 0, 0, 0);
    }
    __syncthreads();
  }
#pragma unroll
  for (int i = 0; i < 4; ++i) {
    int mrow = m0 + wr * 64 + i * 16 + ((l >> 4) << 2);
#pragma unroll
    for (int j = 0; j < 4; ++j) {
      int ncol = n0 + wc * 64 + j * 16 + (l & 15);
      float* cp = C + (size_t)mrow * N + ncol;
#pragma unroll
      for (int r = 0; r < 4; ++r) cp[(size_t)r * N] = acc[i][j][r];
    }
  }
}

// ---------------- fused gmax + conv-bias + relu + pairwise maxpool + transpose ----------------
__global__ __launch_bounds__(256) void k_gfinal(const float* __restrict__ mlpout,
                                                const float* __restrict__ mlp_b,
                                                const int* __restrict__ idxo,
                                                const float* __restrict__ wo,
                                                const float* __restrict__ convb,
                                                const float* __restrict__ cb,
                                                float* __restrict__ out) {
  __shared__ float tile[32][33];
  __shared__ int sj[64][KNB];
  __shared__ float sw[64][KNB];
  int b = blockIdx.z, c0 = blockIdx.y * 32, t20 = blockIdx.x * 32;
  int tid = threadIdx.x;
  int nbase = b * T_DIM + t20 * 2;
  for (int e = tid; e < 64 * KNB; e += 256) {
    int ln = e / KNB, k = e - ln * KNB;
    sj[ln][k] = b * T_DIM + idxo[(size_t)(nbase + ln) * KNB + k];
    sw[ln][k] = wo[(size_t)(nbase + ln) * KNB + k];
  }
  __syncthreads();
  int tx = tid & 31, ty = tid >> 5;
  int c = c0 + tx;
  float bias_c = cb[c];
  float mbias = mlp_b[c];
#pragma unroll
  for (int rr = 0; rr < 4; ++rr) {
    int lt2 = ty + 8 * rr;
    float res[2];
#pragma unroll
    for (int s = 0; s < 2; ++s) {
      int ln = 2 * lt2 + s;
      int n = nbase + ln;
      float q = mlpout[(size_t)n * 512 + 256 + c] + mbias;
      float mx = -3.4e38f;
#pragma unroll
      for (int k = 0; k < KNB; ++k) {
        float v = (mlpout[(size_t)sj[ln][k] * 512 + c] + q) * sw[ln][k];
        mx = fmaxf(mx, v);
      }
      float v = convb[(size_t)n * C_DIM + c] + mx + bias_c;
      res[s] = fmaxf(v, 0.f);
    }
    tile[lt2][tx] = fmaxf(res[0], res[1]);
  }
  __syncthreads();
#pragma unroll
  for (int rr = 0; rr < 4; ++rr) {
    int cc = c0 + ty + 8 * rr;
    out[((size_t)b * C_DIM + cc) * (T_DIM / 2) + t20 + tx] = tile[tx][ty + 8 * rr];
  }
}

// ---------------- merged repack + fixcount zeroing ----------------
__global__ void k_repack(const float* __restrict__ cw, const float* __restrict__ mw,
                         __bf16* __restrict__ wk3, __bf16* __restrict__ mlpB,
                         __bf16* __restrict__ zp, int* __restrict__ fixcount) {
  int i = blockIdx.x * 256 + threadIdx.x;
  if (i == 0) fixcount[0] = 0;
  if (i < 3 * C_DIM * C_DIM) {
    int o = i / 768;
    int rem = i - o * 768;
    int tap = rem >> 8;
    int ii = rem & 255;
    wk3[i] = bfbits(f2bf_rn(cw[(size_t)o * 768 + ii * 3 + tap]));
  } else {
    int m = i - 3 * C_DIM * C_DIM;
    if (m < 512 * 256) {
      int r = m >> 8;
      int col = m & 255;
      mlpB[m] = bfbits(f2bf_rn(mw[(size_t)(r & 255) * 512 + ((r >> 8) << 8) + col]));
    }
  }
  if (blockIdx.x == 0 && threadIdx.x < 128) zp[threadIdx.x] = bfbits(0);
}

extern "C" void kernel_launch(void* const* d_in, const int* in_sizes, int n_in,
                              void* d_out, int out_size, void* d_ws, size_t ws_size,
                              hipStream_t stream) {
  const float* x = (const float*)d_in[0];
  const float* conv_w = (const float*)d_in[2];
  const float* conv_b = (const float*)d_in[3];
  const float* mlp_w = (const float*)d_in[4];
  const float* mlp_b = (const float*)d_in[5];
  float* out = (float*)d_out;

  char* ws = (char*)d_ws;
  size_t off = 0;
  auto alloc = [&](size_t bytes) -> void* {
    void* p = ws + off;
    off += (bytes + 255) & ~(size_t)255;
    return p;
  };
  __bf16* Fh = (__bf16*)alloc((size_t)NPTS * C_DIM * 2);
  __bf16* Fl = (__bf16*)alloc((size_t)NPTS * C_DIM * 2);
  float* convout = (float*)alloc((size_t)NPTS * C_DIM * 4);
  float* mlpout = (float*)alloc((size_t)NPTS * 512 * 4);
  float* sq = (float*)alloc((size_t)NPTS * 4);
  int* idxb = (int*)alloc((size_t)NPTS * KNB * 4);
  float* wb = (float*)alloc((size_t)NPTS * KNB * 4);
  int* fixlist = (int*)alloc((size_t)NPTS * 4);
  int* fixcount = (int*)alloc(256);
  u64* kbuf = (u64*)alloc((size_t)BS * NCH * T_DIM * 8 * 8);   // 16.8 MB
  u64* bbuf = (u64*)alloc((size_t)BS * NCH * T_DIM * 8);       // 2.1 MB
  __bf16* wk3 = (__bf16*)alloc((size_t)3 * C_DIM * C_DIM * 2);
  __bf16* mlpB = (__bf16*)alloc((size_t)512 * 256 * 2);
  __bf16* zp = (__bf16*)alloc(512);

  k_repack<<<dim3(1280), 256, 0, stream>>>(conv_w, mlp_w, wk3, mlpB, zp, fixcount);
  k_transpose_split<<<dim3(T_DIM / 32, C_DIM / 32, BS), 256, 0, stream>>>(x, Fh, Fl);
  k_sq<<<dim3(NPTS / 4), 256, 0, stream>>>(Fh, Fl, sq);

  // gram tile + per-lane min-3 reduce (4096 blocks), then merge, then rare fix
  k_gram_reduce<<<dim3(NCH, T_DIM / 64, BS), 256, 0, stream>>>(Fh, Fl, sq, kbuf, bbuf);
  k_topk_merge<<<dim3(T_DIM / 4, BS), 256, 0, stream>>>(kbuf, bbuf, sq, idxb, wb, fixlist, fixcount);
  k_topk_fix<<<dim3(64), 256, 0, stream>>>(Fh, Fl, sq, fixlist, fixcount, idxb, wb);

  k_gemm_fused<<<dim3(6, NPTS / 128), 256, 0, stream>>>(Fh, mlpB, wk3, mlpout, convout, zp);

  k_gfinal<<<dim3((T_DIM / 2) / 32, C_DIM / 32, BS), 256, 0, stream>>>(
      mlpout, mlp_b, idxb, wb, convout, conv_b, out);
}

// Round 12
// 589.355 us; speedup vs baseline: 1.2221x; 1.2221x over previous
//
#include <hip/hip_runtime.h>
#include <hip/hip_bf16.h>
#include <cstdint>

#define T_DIM 2048
#define C_DIM 256
#define BS 8
#define NPTS (BS * T_DIM)
#define KNB 10
#define NCH 16   // candidate chunks of 128

typedef __bf16 bf16x8 __attribute__((ext_vector_type(8)));
typedef float f32x4 __attribute__((ext_vector_type(4)));
typedef unsigned long long u64;

#define AS1 __attribute__((address_space(1)))
#define AS3 __attribute__((address_space(3)))

__device__ __forceinline__ unsigned short f2bf_rn(float f) {
  unsigned u = __float_as_uint(f);
  unsigned r = (u + 0x7FFFu + ((u >> 16) & 1u)) >> 16;
  return (unsigned short)r;
}
__device__ __forceinline__ float bfbits2f(unsigned short h) {
  return __uint_as_float((unsigned)h << 16);
}
__device__ __forceinline__ __bf16 bfbits(unsigned short h) {
  return __builtin_bit_cast(__bf16, h);
}

// pinned dif computation: identical instruction sequence at every use site.
__device__ __forceinline__ unsigned key_hi(float sqi, float sqj, float gv) {
  float dif = __fmaf_rn(-2.0f, gv, __fadd_rn(sqi, sqj));
  unsigned u = __float_as_uint(dif);
  return (u & 0x80000000u) ? ~u : (u | 0x80000000u);
}

// ---- stage a 128x64 bf16 tile into XOR-swizzled LDS via global_load_lds ----
__device__ __forceinline__ void stage_tile(const __bf16* __restrict__ src, size_t row0,
                                           int ld, int k0, __bf16* lds, int w, int l) {
  int kofs = ((l & 7) ^ (l >> 3)) * 8;
  const __bf16* g0 = src + (row0 + (size_t)(l >> 3)) * ld + k0 + kofs;
  __bf16* lbase = lds + (size_t)(w * 4) * 512;
#pragma unroll
  for (int q4 = 0; q4 < 4; ++q4) {
    __builtin_amdgcn_global_load_lds((AS1 void*)(g0 + (size_t)(w * 4 + q4) * 8 * ld),
                                     (AS3 void*)(lbase + q4 * 512), 16, 0, 0);
  }
}

// ---- stage a 64x64 bf16 tile (row panel) ----
__device__ __forceinline__ void stage_tile64(const __bf16* __restrict__ src, size_t row0,
                                             int k0, __bf16* lds, int w, int l) {
  int kofs = ((l & 7) ^ (l >> 3)) * 8;
  const __bf16* g0 = src + (row0 + (size_t)(l >> 3)) * C_DIM + k0 + kofs;
  __bf16* lbase = lds + (size_t)(w * 2) * 512;
#pragma unroll
  for (int q4 = 0; q4 < 2; ++q4) {
    __builtin_amdgcn_global_load_lds((AS1 void*)(g0 + (size_t)(w * 2 + q4) * 8 * C_DIM),
                                     (AS3 void*)(lbase + q4 * 512), 16, 0, 0);
  }
}

// conv im2col staging: K=768 = 3 taps x 256
__device__ __forceinline__ void stage_tile_conv(const __bf16* __restrict__ src, int m0,
                                                int k0in, const __bf16* __restrict__ zp,
                                                __bf16* lds, int w, int l) {
  int tap = k0in >> 8;
  int kshift = tap - 1;
  int k0 = k0in & 255;
  int kofs = ((l & 7) ^ (l >> 3)) * 8;
  int mb = m0 & (T_DIM - 1);
#pragma unroll
  for (int q4 = 0; q4 < 4; ++q4) {
    int q = w * 4 + q4;
    int row = q * 8 + (l >> 3);
    int t = mb + row + kshift;
    const __bf16* g = ((unsigned)t < (unsigned)T_DIM)
                          ? (src + (size_t)(m0 + row + kshift) * C_DIM + k0 + kofs)
                          : (zp + kofs);
    __builtin_amdgcn_global_load_lds((AS1 void*)g, (AS3 void*)(lds + q * 512), 16, 0, 0);
  }
}

__device__ __forceinline__ bf16x8 read_frag(const __bf16* lds, int t16, int ks, int l) {
  int row = t16 * 16 + (l & 15);
  int kb = ks * 64 + ((l >> 4) << 4);
  int byte = row * 128 + (kb ^ ((row & 7) << 4));
  return *(const bf16x8*)((const char*)lds + byte);
}

// ---------------- transpose + hi/lo bf16 split ----------------
__global__ __launch_bounds__(256) void k_transpose_split(const float* __restrict__ x,
                                                         __bf16* __restrict__ Fh,
                                                         __bf16* __restrict__ Fl) {
  __shared__ float tile[32][33];
  int b = blockIdx.z;
  int t0 = blockIdx.x * 32;
  int c0 = blockIdx.y * 32;
  int tx = threadIdx.x & 31, ty = threadIdx.x >> 5;
  const float* xb = x + (size_t)b * C_DIM * T_DIM;
#pragma unroll
  for (int r = 0; r < 4; ++r) {
    int c = c0 + ty + 8 * r;
    tile[ty + 8 * r][tx] = xb[(size_t)c * T_DIM + t0 + tx];
  }
  __syncthreads();
#pragma unroll
  for (int r = 0; r < 4; ++r) {
    int t = t0 + ty + 8 * r;
    float v = tile[tx][ty + 8 * r];
    unsigned short hb = f2bf_rn(v);
    float lo = v - bfbits2f(hb);
    size_t o = ((size_t)b * T_DIM + t) * C_DIM + c0 + tx;
    Fh[o] = bfbits(hb);
    Fl[o] = bfbits(f2bf_rn(lo));
  }
}

// ---------------- sq[n] = sum_c (hi+lo)^2 ----------------
__global__ __launch_bounds__(256) void k_sq(const __bf16* __restrict__ Fh,
                                            const __bf16* __restrict__ Fl,
                                            float* __restrict__ sq) {
  int n = blockIdx.x * 4 + (threadIdx.x >> 6);
  int lane = threadIdx.x & 63;
  ushort4 hv = ((const ushort4*)Fh)[(size_t)n * 64 + lane];
  ushort4 lv = ((const ushort4*)Fl)[(size_t)n * 64 + lane];
  float s = 0.f;
  {
    float v;
    v = bfbits2f(hv.x) + bfbits2f(lv.x); s = fmaf(v, v, s);
    v = bfbits2f(hv.y) + bfbits2f(lv.y); s = fmaf(v, v, s);
    v = bfbits2f(hv.z) + bfbits2f(lv.z); s = fmaf(v, v, s);
    v = bfbits2f(hv.w) + bfbits2f(lv.w); s = fmaf(v, v, s);
  }
#pragma unroll
  for (int d = 1; d < 64; d <<= 1) s += __shfl_xor(s, d, 64);
  if (lane == 0) sq[n] = s;
}

// ---------------- gram tile + per-lane min-4 reduce (gram never hits HBM) ----------------
// Block = (chunk of 128 cands) x (panel of 64 rows) x batch. Swapped MFMA (cand=A,
// row=B) => lane l of wave w serves row w*16+(l&15); its cands = j*16+(l>>4)*4+r.
// Pass order per k identical to R10/R11 (verified): candhi*rowhi, candhi*rowlo,
// candlo*rowhi. Epilogue: exact per-lane min-4 of its 32 keys; keep 3, bound = 4th.
__global__ __launch_bounds__(256) void k_gram_reduce(const __bf16* __restrict__ Fh,
                                                     const __bf16* __restrict__ Fl,
                                                     const float* __restrict__ sq,
                                                     u64* __restrict__ kbuf,
                                                     u64* __restrict__ bbuf) {
  __shared__ __bf16 Bh[128 * 64], Bl[128 * 64];   // cand tiles (hi/lo)
  __shared__ __bf16 Rh[64 * 64], Rl[64 * 64];     // row tiles (hi/lo)
  __shared__ float sqc[128];

  int ch = blockIdx.x, p = blockIdx.y, b = blockIdx.z;
  size_t base = (size_t)b * T_DIM;
  const float* sqb = sq + base;
  int tid = threadIdx.x, w = tid >> 6, l = tid & 63, g = l >> 4;
  int r0 = p * 64;
  int cand0 = ch * 128;
  int myrow = r0 + w * 16 + (l & 15);
  float sqi = sqb[myrow];
  if (tid < 128) sqc[tid] = sqb[cand0 + tid];

  f32x4 acc[8];
#pragma unroll
  for (int j = 0; j < 8; ++j) acc[j] = {0.f, 0.f, 0.f, 0.f};

  for (int k0 = 0; k0 < C_DIM; k0 += 64) {
    stage_tile(Fh, base + cand0, C_DIM, k0, Bh, w, l);
    stage_tile(Fl, base + cand0, C_DIM, k0, Bl, w, l);
    stage_tile64(Fh, base + r0, k0, Rh, w, l);
    stage_tile64(Fl, base + r0, k0, Rl, w, l);
    __syncthreads();
#pragma unroll
    for (int ks = 0; ks < 2; ++ks) {
      bf16x8 rh = read_frag(Rh, w, ks, l);
      bf16x8 rl = read_frag(Rl, w, ks, l);
      bf16x8 cv[8];
#pragma unroll
      for (int j = 0; j < 8; ++j) cv[j] = read_frag(Bh, j, ks, l);
#pragma unroll
      for (int j = 0; j < 8; ++j)
        acc[j] = __builtin_amdgcn_mfma_f32_16x16x32_bf16(cv[j], rh, acc[j], 0, 0, 0);
#pragma unroll
      for (int j = 0; j < 8; ++j)
        acc[j] = __builtin_amdgcn_mfma_f32_16x16x32_bf16(cv[j], rl, acc[j], 0, 0, 0);
#pragma unroll
      for (int j = 0; j < 8; ++j) cv[j] = read_frag(Bl, j, ks, l);
#pragma unroll
      for (int j = 0; j < 8; ++j)
        acc[j] = __builtin_amdgcn_mfma_f32_16x16x32_bf16(cv[j], rh, acc[j], 0, 0, 0);
    }
    __syncthreads();
  }

  // exact per-lane min-4 over this lane's 32 scores
  u64 c0 = ~0ull, c1 = ~0ull, c2 = ~0ull, c3 = ~0ull;
#pragma unroll
  for (int j = 0; j < 8; ++j) {
    f32x4 sv = *(const f32x4*)&sqc[j * 16 + (g << 2)];
#pragma unroll
    for (int r = 0; r < 4; ++r) {
      unsigned u = key_hi(sqi, sv[r], acc[j][r]);
      u64 key = ((u64)u << 32) | (unsigned)(cand0 + j * 16 + (g << 2) + r);
      u64 t1 = (key > c0) ? key : c0; c0 = (key < c0) ? key : c0;
      u64 t2 = (t1 > c1) ? t1 : c1;  c1 = (t1 < c1) ? t1 : c1;
      u64 t3 = (t2 > c2) ? t2 : c2;  c2 = (t2 < c2) ? t2 : c2;
      c3 = (t3 < c3) ? t3 : c3;
    }
  }
  // keys: 3 kept per (row, chunk, quarter)
  u64* kp = kbuf + ((((size_t)b * NCH + ch) * T_DIM + myrow) * 12 + g * 3);
  kp[0] = c0;
  kp[1] = c1;
  kp[2] = c2;
  // bound: min over quarters of the 4th-smallest
  u64 bd = c3;
  { u64 o = __shfl_xor(bd, 16, 64); bd = (o < bd) ? o : bd; }
  { u64 o = __shfl_xor(bd, 32, 64); bd = (o < bd) ? o : bd; }
  if (g == 0) bbuf[((size_t)b * NCH + ch) * T_DIM + myrow] = bd;
}

// ---------------- merge: 192 kept keys/row -> top-10 + theta + flag ----------------
__global__ __launch_bounds__(256) void k_topk_merge(const u64* __restrict__ kbuf,
                                                    const u64* __restrict__ bbuf,
                                                    const float* __restrict__ sq,
                                                    int* __restrict__ idxo,
                                                    float* __restrict__ wo,
                                                    int* __restrict__ fixlist,
                                                    int* __restrict__ fixcount) {
  int b = blockIdx.y;
  int row = blockIdx.x * 4 + (threadIdx.x >> 6);
  int lane = threadIdx.x & 63;
  const float* sqb = sq + (size_t)b * T_DIM;
  float sqi = sqb[row];

  // lane covers (chunk = lane>>2, quarter = lane&3): its kept min-3
  const u64* kp = kbuf + ((((size_t)b * NCH + (lane >> 2)) * T_DIM + row) * 12 + (lane & 3) * 3);
  u64 m0 = kp[0], m1 = kp[1], m2 = kp[2];
  u64 excl = (lane < NCH) ? bbuf[((size_t)b * NCH + lane) * T_DIM + row] : ~0ull;

  // 10-round extract-min (u32 hi butterfly, then lo among hi-matching)
  u64 win[KNB];
#pragma unroll
  for (int s = 0; s < KNB; ++s) {
    unsigned mh = (unsigned)(m0 >> 32);
    unsigned h = mh;
#pragma unroll
    for (int d = 1; d < 64; d <<= 1) {
      unsigned oh = __shfl_xor(h, d, 64);
      h = (oh < h) ? oh : h;
    }
    unsigned lo = (mh == h) ? (unsigned)m0 : 0xFFFFFFFFu;
#pragma unroll
    for (int d = 1; d < 64; d <<= 1) {
      unsigned ol = __shfl_xor(lo, d, 64);
      lo = (ol < lo) ? ol : lo;
    }
    u64 m = ((u64)h << 32) | lo;
    win[s] = m;
    bool pop = (m0 == m);
    m0 = pop ? m1 : m0;
    m1 = pop ? m2 : m1;
    m2 = pop ? ~0ull : m2;
  }
  u64 theta = win[KNB - 1];

  // parallel epilogue: lane s writes winner s (output order-invariant: max over k)
  u64 mywin = win[0];
#pragma unroll
  for (int s = 1; s < KNB; ++s) mywin = (lane == s) ? win[s] : mywin;
  if (lane < KNB) {
    int j = (int)(unsigned)(mywin & 0xffffffffull);
    unsigned su = (unsigned)(mywin >> 32);
    unsigned bits = (su & 0x80000000u) ? (su & 0x7fffffffu) : ~su;
    float dif = __uint_as_float(bits);
    float sqj = sqb[j];
    float num = 0.5f * (sqi + sqj - dif);
    float wv = num / (sqrtf(sqi) * sqrtf(sqj));
    idxo[((size_t)b * T_DIM + row) * KNB + lane] = j;
    wo[((size_t)b * T_DIM + row) * KNB + lane] = wv;
  }

  // flag iff smallest excluded bound < theta
#pragma unroll
  for (int d = 1; d < 64; d <<= 1) {
    u64 o = __shfl_xor(excl, d, 64);
    excl = (o < excl) ? o : excl;
  }
  if (lane == 0 && excl < theta) {
    int slot = atomicAdd(fixcount, 1);
    fixlist[slot] = (int)(b * T_DIM + row);
  }
}

// ---------------- FIX kernel: recompute flagged rows exactly (fp32, parallel) ----------------
// One block per flagged row (grid-stride). Wave-per-candidate dots: lane l covers
// dims 4l..4l+3 (coalesced 8B loads), 6-step shuffle reduce.
__global__ __launch_bounds__(256) void k_topk_fix(const __bf16* __restrict__ Fh,
                                                  const __bf16* __restrict__ Fl,
                                                  const float* __restrict__ sq,
                                                  const int* __restrict__ fixlist,
                                                  const int* __restrict__ fixcount,
                                                  int* __restrict__ idxo,
                                                  float* __restrict__ wo) {
  __shared__ float xr[C_DIM];
  __shared__ float difs[T_DIM];
  int n = fixcount[0];
  int tid = threadIdx.x;
  int w = tid >> 6, lane = tid & 63;
  const unsigned short* fh = (const unsigned short*)Fh;
  const unsigned short* fl = (const unsigned short*)Fl;
  for (int i = blockIdx.x; i < n; i += gridDim.x) {
    int rowg = fixlist[i];
    int b = rowg >> 11, r = rowg & (T_DIM - 1);
    xr[tid] = bfbits2f(fh[(size_t)rowg * C_DIM + tid]) + bfbits2f(fl[(size_t)rowg * C_DIM + tid]);
    __syncthreads();
    const float* sqb = sq + (size_t)b * T_DIM;
    float sqi = sqb[r];
    // wave w handles candidates [w*512, w*512+512) in steps of... 4 waves? (256 thr = 4 waves)
    // 4 waves x 512 candidates each
    for (int jj = 0; jj < 512; ++jj) {
      int j = w * 512 + jj;
      ushort4 h4 = *(const ushort4*)(fh + ((size_t)b * T_DIM + j) * C_DIM + lane * 4);
      ushort4 l4 = *(const ushort4*)(fl + ((size_t)b * T_DIM + j) * C_DIM + lane * 4);
      float part = 0.f;
      part = fmaf(bfbits2f(h4.x) + bfbits2f(l4.x), xr[lane * 4 + 0], part);
      part = fmaf(bfbits2f(h4.y) + bfbits2f(l4.y), xr[lane * 4 + 1], part);
      part = fmaf(bfbits2f(h4.z) + bfbits2f(l4.z), xr[lane * 4 + 2], part);
      part = fmaf(bfbits2f(h4.w) + bfbits2f(l4.w), xr[lane * 4 + 3], part);
#pragma unroll
      for (int d = 1; d < 64; d <<= 1) part += __shfl_xor(part, d, 64);
      if (lane == 0) difs[j] = __fmaf_rn(-2.0f, part, __fadd_rn(sqi, sqb[j]));
    }
    __syncthreads();
    if (tid < 64) {
      u64 b0 = ~0ull, b1 = ~0ull, b2 = ~0ull, b3 = ~0ull, b4 = ~0ull,
          b5 = ~0ull, b6 = ~0ull, b7 = ~0ull, b8 = ~0ull, b9 = ~0ull;
      for (int t = 0; t < 32; ++t) {
        unsigned j = (unsigned)(lane + 64 * t);
        unsigned u = __float_as_uint(difs[j]);
        u = (u & 0x80000000u) ? ~u : (u | 0x80000000u);
        u64 key = ((u64)u << 32) | j;
        if (key < b9) {
          b9 = key;
          u64 tt;
          if (b9 < b8) { tt = b8; b8 = b9; b9 = tt; }
          if (b8 < b7) { tt = b7; b7 = b8; b8 = tt; }
          if (b7 < b6) { tt = b6; b6 = b7; b7 = tt; }
          if (b6 < b5) { tt = b5; b5 = b6; b6 = tt; }
          if (b5 < b4) { tt = b4; b4 = b5; b5 = tt; }
          if (b4 < b3) { tt = b3; b3 = b4; b4 = tt; }
          if (b3 < b2) { tt = b2; b2 = b3; b3 = tt; }
          if (b2 < b1) { tt = b1; b1 = b2; b2 = tt; }
          if (b1 < b0) { tt = b0; b0 = b1; b1 = tt; }
        }
      }
      int* idxb = idxo + (size_t)b * T_DIM * KNB;
      float* wbp = wo + (size_t)b * T_DIM * KNB;
#pragma unroll
      for (int s = 0; s < KNB; ++s) {
        u64 m = b0;
#pragma unroll
        for (int d = 1; d < 64; d <<= 1) {
          u64 o = __shfl_xor(m, d, 64);
          m = (o < m) ? o : m;
        }
        u64 bal = __ballot(b0 == m);
        int leader = (int)__builtin_ctzll(bal);
        if (lane == leader) {
          b0 = b1; b1 = b2; b2 = b3; b3 = b4; b4 = b5;
          b5 = b6; b6 = b7; b7 = b8; b8 = b9; b9 = ~0ull;
        }
        if (lane == 0) {
          int j = (int)(unsigned)(m & 0xffffffffull);
          unsigned su = (unsigned)(m >> 32);
          unsigned bits = (su & 0x80000000u) ? (su & 0x7fffffffu) : ~su;
          float dif = __uint_as_float(bits);
          float sqj = sqb[j];
          float num = 0.5f * (sqi + sqj - dif);
          float wv = num / (sqrtf(sqi) * sqrtf(sqj));
          idxb[(size_t)r * KNB + s] = j;
          wbp[(size_t)r * KNB + s] = wv;
        }
      }
    }
    __syncthreads();
  }
}

// ---------------- merged bf16 GEMM dispatch: blocks 0-3 MLP, 4-5 conv ----------------
__global__ __launch_bounds__(256, 2) void k_gemm_fused(const __bf16* __restrict__ Fh,
                                                       const __bf16* __restrict__ mlpB,
                                                       const __bf16* __restrict__ wk3,
                                                       float* __restrict__ mlpout,
                                                       float* __restrict__ convout,
                                                       const __bf16* __restrict__ zp) {
  __shared__ __bf16 As[128 * 64], Bs[128 * 64];
  int bx = blockIdx.x;
  const __bf16* Bm;
  float* C;
  int N, K, conv, n0;
  if (bx < 4) {
    Bm = mlpB; C = mlpout; N = 512; K = 256; conv = 0; n0 = bx * 128;
  } else {
    Bm = wk3; C = convout; N = 256; K = 768; conv = 1; n0 = (bx - 4) * 128;
  }
  int m0 = blockIdx.y * 128;
  int tid = threadIdx.x, w = tid >> 6, l = tid & 63;
  int wr = w >> 1, wc = w & 1;
  f32x4 acc[4][4];
#pragma unroll
  for (int i = 0; i < 4; ++i)
#pragma unroll
    for (int j = 0; j < 4; ++j) acc[i][j] = {0.f, 0.f, 0.f, 0.f};

  for (int k0 = 0; k0 < K; k0 += 64) {
    if (conv)
      stage_tile_conv(Fh, m0, k0, zp, As, w, l);
    else
      stage_tile(Fh, (size_t)m0, C_DIM, k0, As, w, l);
    stage_tile(Bm, (size_t)n0, K, k0, Bs, w, l);
    __syncthreads();
#pragma unroll
    for (int ks = 0; ks < 2; ++ks) {
      bf16x8 af[4], bf_[4];
#pragma unroll
      for (int i = 0; i < 4; ++i) af[i] = read_frag(As, wr * 4 + i, ks, l);
#pragma unroll
      for (int j = 0; j < 4; ++j) bf_[j] = read_frag(Bs, wc * 4 + j, ks, l);
#pragma unroll
      for (int i = 0; i < 4; ++i)
#pragma unroll
        for (int j = 0; j < 4; ++j)
          acc[i][j] = __builtin_amdgcn_mfma_f32_16x16x32_bf16(af[i], bf_[j], acc[i][j], 0, 0, 0);
    }
    __syncthreads();
  }
#pragma unroll
  for (int i = 0; i < 4; ++i) {
    int mrow = m0 + wr * 64 + i * 16 + ((l >> 4) << 2);
#pragma unroll
    for (int j = 0; j < 4; ++j) {
      int ncol = n0 + wc * 64 + j * 16 + (l & 15);
      float* cp = C + (size_t)mrow * N + ncol;
#pragma unroll
      for (int r = 0; r < 4; ++r) cp[(size_t)r * N] = acc[i][j][r];
    }
  }
}

// ---------------- fused gmax + conv-bias + relu + pairwise maxpool + transpose ----------------
__global__ __launch_bounds__(256) void k_gfinal(const float* __restrict__ mlpout,
                                                const float* __restrict__ mlp_b,
                                                const int* __restrict__ idxo,
                                                const float* __restrict__ wo,
                                                const float* __restrict__ convb,
                                                const float* __restrict__ cb,
                                                float* __restrict__ out) {
  __shared__ float tile[32][33];
  __shared__ int sj[64][KNB];
  __shared__ float sw[64][KNB];
  int b = blockIdx.z, c0 = blockIdx.y * 32, t20 = blockIdx.x * 32;
  int tid = threadIdx.x;
  int nbase = b * T_DIM + t20 * 2;
  for (int e = tid; e < 64 * KNB; e += 256) {
    int ln = e / KNB, k = e - ln * KNB;
    sj[ln][k] = b * T_DIM + idxo[(size_t)(nbase + ln) * KNB + k];
    sw[ln][k] = wo[(size_t)(nbase + ln) * KNB + k];
  }
  __syncthreads();
  int tx = tid & 31, ty = tid >> 5;
  int c = c0 + tx;
  float bias_c = cb[c];
  float mbias = mlp_b[c];
#pragma unroll
  for (int rr = 0; rr < 4; ++rr) {
    int lt2 = ty + 8 * rr;
    float res[2];
#pragma unroll
    for (int s = 0; s < 2; ++s) {
      int ln = 2 * lt2 + s;
      int n = nbase + ln;
      float q = mlpout[(size_t)n * 512 + 256 + c] + mbias;
      float mx = -3.4e38f;
#pragma unroll
      for (int k = 0; k < KNB; ++k) {
        float v = (mlpout[(size_t)sj[ln][k] * 512 + c] + q) * sw[ln][k];
        mx = fmaxf(mx, v);
      }
      float v = convb[(size_t)n * C_DIM + c] + mx + bias_c;
      res[s] = fmaxf(v, 0.f);
    }
    tile[lt2][tx] = fmaxf(res[0], res[1]);
  }
  __syncthreads();
#pragma unroll
  for (int rr = 0; rr < 4; ++rr) {
    int cc = c0 + ty + 8 * rr;
    out[((size_t)b * C_DIM + cc) * (T_DIM / 2) + t20 + tx] = tile[tx][ty + 8 * rr];
  }
}

// ---------------- merged repack + fixcount zeroing ----------------
__global__ void k_repack(const float* __restrict__ cw, const float* __restrict__ mw,
                         __bf16* __restrict__ wk3, __bf16* __restrict__ mlpB,
                         __bf16* __restrict__ zp, int* __restrict__ fixcount) {
  int i = blockIdx.x * 256 + threadIdx.x;
  if (i == 0) fixcount[0] = 0;
  if (i < 3 * C_DIM * C_DIM) {
    int o = i / 768;
    int rem = i - o * 768;
    int tap = rem >> 8;
    int ii = rem & 255;
    wk3[i] = bfbits(f2bf_rn(cw[(size_t)o * 768 + ii * 3 + tap]));
  } else {
    int m = i - 3 * C_DIM * C_DIM;
    if (m < 512 * 256) {
      int r = m >> 8;
      int col = m & 255;
      mlpB[m] = bfbits(f2bf_rn(mw[(size_t)(r & 255) * 512 + ((r >> 8) << 8) + col]));
    }
  }
  if (blockIdx.x == 0 && threadIdx.x < 128) zp[threadIdx.x] = bfbits(0);
}

extern "C" void kernel_launch(void* const* d_in, const int* in_sizes, int n_in,
                              void* d_out, int out_size, void* d_ws, size_t ws_size,
                              hipStream_t stream) {
  const float* x = (const float*)d_in[0];
  const float* conv_w = (const float*)d_in[2];
  const float* conv_b = (const float*)d_in[3];
  const float* mlp_w = (const float*)d_in[4];
  const float* mlp_b = (const float*)d_in[5];
  float* out = (float*)d_out;

  char* ws = (char*)d_ws;
  size_t off = 0;
  auto alloc = [&](size_t bytes) -> void* {
    void* p = ws + off;
    off += (bytes + 255) & ~(size_t)255;
    return p;
  };
  __bf16* Fh = (__bf16*)alloc((size_t)NPTS * C_DIM * 2);
  __bf16* Fl = (__bf16*)alloc((size_t)NPTS * C_DIM * 2);
  float* convout = (float*)alloc((size_t)NPTS * C_DIM * 4);
  float* mlpout = (float*)alloc((size_t)NPTS * 512 * 4);
  float* sq = (float*)alloc((size_t)NPTS * 4);
  int* idxb = (int*)alloc((size_t)NPTS * KNB * 4);
  float* wb = (float*)alloc((size_t)NPTS * KNB * 4);
  int* fixlist = (int*)alloc((size_t)NPTS * 4);
  int* fixcount = (int*)alloc(256);
  u64* kbuf = (u64*)alloc((size_t)BS * NCH * T_DIM * 12 * 8);  // 25.2 MB
  u64* bbuf = (u64*)alloc((size_t)BS * NCH * T_DIM * 8);       // 2.1 MB
  __bf16* wk3 = (__bf16*)alloc((size_t)3 * C_DIM * C_DIM * 2);
  __bf16* mlpB = (__bf16*)alloc((size_t)512 * 256 * 2);
  __bf16* zp = (__bf16*)alloc(512);

  k_repack<<<dim3(1280), 256, 0, stream>>>(conv_w, mlp_w, wk3, mlpB, zp, fixcount);
  k_transpose_split<<<dim3(T_DIM / 32, C_DIM / 32, BS), 256, 0, stream>>>(x, Fh, Fl);
  k_sq<<<dim3(NPTS / 4), 256, 0, stream>>>(Fh, Fl, sq);

  // gram tile + per-lane min-4 reduce (4096 blocks), then merge, then rare fix
  k_gram_reduce<<<dim3(NCH, T_DIM / 64, BS), 256, 0, stream>>>(Fh, Fl, sq, kbuf, bbuf);
  k_topk_merge<<<dim3(T_DIM / 4, BS), 256, 0, stream>>>(kbuf, bbuf, sq, idxb, wb, fixlist, fixcount);
  k_topk_fix<<<dim3(256), 256, 0, stream>>>(Fh, Fl, sq, fixlist, fixcount, idxb, wb);

  k_gemm_fused<<<dim3(6, NPTS / 128), 256, 0, stream>>>(Fh, mlpB, wk3, mlpout, convout, zp);

  k_gfinal<<<dim3((T_DIM / 2) / 32, C_DIM / 32, BS), 256, 0, stream>>>(
      mlpout, mlp_b, idxb, wb, convout, conv_b, out);
}

// Round 13
// 290.669 us; speedup vs baseline: 2.4778x; 2.0276x over previous
//
#include <hip/hip_runtime.h>
#include <hip/hip_bf16.h>
#include <cstdint>

#define T_DIM 2048
#define C_DIM 256
#define BS 8
#define NPTS (BS * T_DIM)
#define KNB 10
#define NCH 16   // candidate chunks of 128

typedef __bf16 bf16x8 __attribute__((ext_vector_type(8)));
typedef float f32x4 __attribute__((ext_vector_type(4)));
typedef unsigned long long u64;

#define AS1 __attribute__((address_space(1)))
#define AS3 __attribute__((address_space(3)))

__device__ __forceinline__ unsigned short f2bf_rn(float f) {
  unsigned u = __float_as_uint(f);
  unsigned r = (u + 0x7FFFu + ((u >> 16) & 1u)) >> 16;
  return (unsigned short)r;
}
__device__ __forceinline__ float bfbits2f(unsigned short h) {
  return __uint_as_float((unsigned)h << 16);
}
__device__ __forceinline__ __bf16 bfbits(unsigned short h) {
  return __builtin_bit_cast(__bf16, h);
}

// pinned dif computation: identical instruction sequence at every use site.
__device__ __forceinline__ unsigned key_hi(float sqi, float sqj, float gv) {
  float dif = __fmaf_rn(-2.0f, gv, __fadd_rn(sqi, sqj));
  unsigned u = __float_as_uint(dif);
  return (u & 0x80000000u) ? ~u : (u | 0x80000000u);
}

// ---- stage a 128x64 bf16 tile into XOR-swizzled LDS via global_load_lds ----
__device__ __forceinline__ void stage_tile(const __bf16* __restrict__ src, size_t row0,
                                           int ld, int k0, __bf16* lds, int w, int l) {
  int kofs = ((l & 7) ^ (l >> 3)) * 8;
  const __bf16* g0 = src + (row0 + (size_t)(l >> 3)) * ld + k0 + kofs;
  __bf16* lbase = lds + (size_t)(w * 4) * 512;
#pragma unroll
  for (int q4 = 0; q4 < 4; ++q4) {
    __builtin_amdgcn_global_load_lds((AS1 void*)(g0 + (size_t)(w * 4 + q4) * 8 * ld),
                                     (AS3 void*)(lbase + q4 * 512), 16, 0, 0);
  }
}

// ---- stage a 64x64 bf16 tile (row panel) ----
__device__ __forceinline__ void stage_tile64(const __bf16* __restrict__ src, size_t row0,
                                             int k0, __bf16* lds, int w, int l) {
  int kofs = ((l & 7) ^ (l >> 3)) * 8;
  const __bf16* g0 = src + (row0 + (size_t)(l >> 3)) * C_DIM + k0 + kofs;
  __bf16* lbase = lds + (size_t)(w * 2) * 512;
#pragma unroll
  for (int q4 = 0; q4 < 2; ++q4) {
    __builtin_amdgcn_global_load_lds((AS1 void*)(g0 + (size_t)(w * 2 + q4) * 8 * C_DIM),
                                     (AS3 void*)(lbase + q4 * 512), 16, 0, 0);
  }
}

// conv im2col staging: K=768 = 3 taps x 256
__device__ __forceinline__ void stage_tile_conv(const __bf16* __restrict__ src, int m0,
                                                int k0in, const __bf16* __restrict__ zp,
                                                __bf16* lds, int w, int l) {
  int tap = k0in >> 8;
  int kshift = tap - 1;
  int k0 = k0in & 255;
  int kofs = ((l & 7) ^ (l >> 3)) * 8;
  int mb = m0 & (T_DIM - 1);
#pragma unroll
  for (int q4 = 0; q4 < 4; ++q4) {
    int q = w * 4 + q4;
    int row = q * 8 + (l >> 3);
    int t = mb + row + kshift;
    const __bf16* g = ((unsigned)t < (unsigned)T_DIM)
                          ? (src + (size_t)(m0 + row + kshift) * C_DIM + k0 + kofs)
                          : (zp + kofs);
    __builtin_amdgcn_global_load_lds((AS1 void*)g, (AS3 void*)(lds + q * 512), 16, 0, 0);
  }
}

__device__ __forceinline__ bf16x8 read_frag(const __bf16* lds, int t16, int ks, int l) {
  int row = t16 * 16 + (l & 15);
  int kb = ks * 64 + ((l >> 4) << 4);
  int byte = row * 128 + (kb ^ ((row & 7) << 4));
  return *(const bf16x8*)((const char*)lds + byte);
}

// ---------------- transpose + hi/lo bf16 split ----------------
__global__ __launch_bounds__(256) void k_transpose_split(const float* __restrict__ x,
                                                         __bf16* __restrict__ Fh,
                                                         __bf16* __restrict__ Fl) {
  __shared__ float tile[32][33];
  int b = blockIdx.z;
  int t0 = blockIdx.x * 32;
  int c0 = blockIdx.y * 32;
  int tx = threadIdx.x & 31, ty = threadIdx.x >> 5;
  const float* xb = x + (size_t)b * C_DIM * T_DIM;
#pragma unroll
  for (int r = 0; r < 4; ++r) {
    int c = c0 + ty + 8 * r;
    tile[ty + 8 * r][tx] = xb[(size_t)c * T_DIM + t0 + tx];
  }
  __syncthreads();
#pragma unroll
  for (int r = 0; r < 4; ++r) {
    int t = t0 + ty + 8 * r;
    float v = tile[tx][ty + 8 * r];
    unsigned short hb = f2bf_rn(v);
    float lo = v - bfbits2f(hb);
    size_t o = ((size_t)b * T_DIM + t) * C_DIM + c0 + tx;
    Fh[o] = bfbits(hb);
    Fl[o] = bfbits(f2bf_rn(lo));
  }
}

// ---------------- sq[n] = sum_c (hi+lo)^2 ----------------
__global__ __launch_bounds__(256) void k_sq(const __bf16* __restrict__ Fh,
                                            const __bf16* __restrict__ Fl,
                                            float* __restrict__ sq) {
  int n = blockIdx.x * 4 + (threadIdx.x >> 6);
  int lane = threadIdx.x & 63;
  ushort4 hv = ((const ushort4*)Fh)[(size_t)n * 64 + lane];
  ushort4 lv = ((const ushort4*)Fl)[(size_t)n * 64 + lane];
  float s = 0.f;
  {
    float v;
    v = bfbits2f(hv.x) + bfbits2f(lv.x); s = fmaf(v, v, s);
    v = bfbits2f(hv.y) + bfbits2f(lv.y); s = fmaf(v, v, s);
    v = bfbits2f(hv.z) + bfbits2f(lv.z); s = fmaf(v, v, s);
    v = bfbits2f(hv.w) + bfbits2f(lv.w); s = fmaf(v, v, s);
  }
#pragma unroll
  for (int d = 1; d < 64; d <<= 1) s += __shfl_xor(s, d, 64);
  if (lane == 0) sq[n] = s;
}

// ---------------- gram tile + per-lane min-4 reduce (gram never hits HBM) ----------------
// Block = (chunk of 128 cands) x (panel of 64 rows) x batch. Swapped MFMA (cand=A,
// row=B) => lane l of wave w serves row w*16+(l&15); its cands = j*16+(l>>4)*4+r.
// Pass order per k identical to R10-R12 (verified): candhi*rowhi, candhi*rowlo,
// candlo*rowhi. Epilogue: exact per-lane min-4 of its 32 keys; keep 3, bound = 4th.
__global__ __launch_bounds__(256) void k_gram_reduce(const __bf16* __restrict__ Fh,
                                                     const __bf16* __restrict__ Fl,
                                                     const float* __restrict__ sq,
                                                     u64* __restrict__ kbuf,
                                                     u64* __restrict__ bbuf) {
  __shared__ __bf16 Bh[128 * 64], Bl[128 * 64];   // cand tiles (hi/lo)
  __shared__ __bf16 Rh[64 * 64], Rl[64 * 64];     // row tiles (hi/lo)
  __shared__ float sqc[128];

  int ch = blockIdx.x, p = blockIdx.y, b = blockIdx.z;
  size_t base = (size_t)b * T_DIM;
  const float* sqb = sq + base;
  int tid = threadIdx.x, w = tid >> 6, l = tid & 63, g = l >> 4;
  int r0 = p * 64;
  int cand0 = ch * 128;
  int myrow = r0 + w * 16 + (l & 15);
  float sqi = sqb[myrow];
  if (tid < 128) sqc[tid] = sqb[cand0 + tid];

  f32x4 acc[8];
#pragma unroll
  for (int j = 0; j < 8; ++j) acc[j] = {0.f, 0.f, 0.f, 0.f};

  for (int k0 = 0; k0 < C_DIM; k0 += 64) {
    stage_tile(Fh, base + cand0, C_DIM, k0, Bh, w, l);
    stage_tile(Fl, base + cand0, C_DIM, k0, Bl, w, l);
    stage_tile64(Fh, base + r0, k0, Rh, w, l);
    stage_tile64(Fl, base + r0, k0, Rl, w, l);
    __syncthreads();
#pragma unroll
    for (int ks = 0; ks < 2; ++ks) {
      bf16x8 rh = read_frag(Rh, w, ks, l);
      bf16x8 rl = read_frag(Rl, w, ks, l);
      bf16x8 cv[8];
#pragma unroll
      for (int j = 0; j < 8; ++j) cv[j] = read_frag(Bh, j, ks, l);
#pragma unroll
      for (int j = 0; j < 8; ++j)
        acc[j] = __builtin_amdgcn_mfma_f32_16x16x32_bf16(cv[j], rh, acc[j], 0, 0, 0);
#pragma unroll
      for (int j = 0; j < 8; ++j)
        acc[j] = __builtin_amdgcn_mfma_f32_16x16x32_bf16(cv[j], rl, acc[j], 0, 0, 0);
#pragma unroll
      for (int j = 0; j < 8; ++j) cv[j] = read_frag(Bl, j, ks, l);
#pragma unroll
      for (int j = 0; j < 8; ++j)
        acc[j] = __builtin_amdgcn_mfma_f32_16x16x32_bf16(cv[j], rh, acc[j], 0, 0, 0);
    }
    __syncthreads();
  }

  // exact per-lane min-4 over this lane's 32 scores
  u64 c0 = ~0ull, c1 = ~0ull, c2 = ~0ull, c3 = ~0ull;
#pragma unroll
  for (int j = 0; j < 8; ++j) {
    f32x4 sv = *(const f32x4*)&sqc[j * 16 + (g << 2)];
#pragma unroll
    for (int r = 0; r < 4; ++r) {
      unsigned u = key_hi(sqi, sv[r], acc[j][r]);
      u64 key = ((u64)u << 32) | (unsigned)(cand0 + j * 16 + (g << 2) + r);
      u64 t1 = (key > c0) ? key : c0; c0 = (key < c0) ? key : c0;
      u64 t2 = (t1 > c1) ? t1 : c1;  c1 = (t1 < c1) ? t1 : c1;
      u64 t3 = (t2 > c2) ? t2 : c2;  c2 = (t2 < c2) ? t2 : c2;
      c3 = (t3 < c3) ? t3 : c3;
    }
  }
  // keys: 3 kept per (row, chunk, quarter)
  u64* kp = kbuf + ((((size_t)b * NCH + ch) * T_DIM + myrow) * 12 + g * 3);
  kp[0] = c0;
  kp[1] = c1;
  kp[2] = c2;
  // bound: min over quarters of the 4th-smallest
  u64 bd = c3;
  { u64 o = __shfl_xor(bd, 16, 64); bd = (o < bd) ? o : bd; }
  { u64 o = __shfl_xor(bd, 32, 64); bd = (o < bd) ? o : bd; }
  if (g == 0) bbuf[((size_t)b * NCH + ch) * T_DIM + myrow] = bd;
}

// ---------------- merge: 192 kept keys/row -> top-10 + theta + flag ----------------
__global__ __launch_bounds__(256) void k_topk_merge(const u64* __restrict__ kbuf,
                                                    const u64* __restrict__ bbuf,
                                                    const float* __restrict__ sq,
                                                    int* __restrict__ idxo,
                                                    float* __restrict__ wo,
                                                    int* __restrict__ fixlist,
                                                    int* __restrict__ fixcount) {
  int b = blockIdx.y;
  int row = blockIdx.x * 4 + (threadIdx.x >> 6);
  int lane = threadIdx.x & 63;
  const float* sqb = sq + (size_t)b * T_DIM;
  float sqi = sqb[row];

  // lane covers (chunk = lane>>2, quarter = lane&3): its kept min-3
  const u64* kp = kbuf + ((((size_t)b * NCH + (lane >> 2)) * T_DIM + row) * 12 + (lane & 3) * 3);
  u64 m0 = kp[0], m1 = kp[1], m2 = kp[2];
  u64 excl = (lane < NCH) ? bbuf[((size_t)b * NCH + lane) * T_DIM + row] : ~0ull;

  // 10-round extract-min (u32 hi butterfly, then lo among hi-matching)
  u64 win[KNB];
#pragma unroll
  for (int s = 0; s < KNB; ++s) {
    unsigned mh = (unsigned)(m0 >> 32);
    unsigned h = mh;
#pragma unroll
    for (int d = 1; d < 64; d <<= 1) {
      unsigned oh = __shfl_xor(h, d, 64);
      h = (oh < h) ? oh : h;
    }
    unsigned lo = (mh == h) ? (unsigned)m0 : 0xFFFFFFFFu;
#pragma unroll
    for (int d = 1; d < 64; d <<= 1) {
      unsigned ol = __shfl_xor(lo, d, 64);
      lo = (ol < lo) ? ol : lo;
    }
    u64 m = ((u64)h << 32) | lo;
    win[s] = m;
    bool pop = (m0 == m);
    m0 = pop ? m1 : m0;
    m1 = pop ? m2 : m1;
    m2 = pop ? ~0ull : m2;
  }
  u64 theta = win[KNB - 1];

  // parallel epilogue: lane s writes winner s (output order-invariant: max over k)
  u64 mywin = win[0];
#pragma unroll
  for (int s = 1; s < KNB; ++s) mywin = (lane == s) ? win[s] : mywin;
  if (lane < KNB) {
    int j = (int)(unsigned)(mywin & 0xffffffffull);
    unsigned su = (unsigned)(mywin >> 32);
    unsigned bits = (su & 0x80000000u) ? (su & 0x7fffffffu) : ~su;
    float dif = __uint_as_float(bits);
    float sqj = sqb[j];
    float num = 0.5f * (sqi + sqj - dif);
    float wv = num / (sqrtf(sqi) * sqrtf(sqj));
    idxo[((size_t)b * T_DIM + row) * KNB + lane] = j;
    wo[((size_t)b * T_DIM + row) * KNB + lane] = wv;
  }

  // flag iff smallest excluded bound < theta
#pragma unroll
  for (int d = 1; d < 64; d <<= 1) {
    u64 o = __shfl_xor(excl, d, 64);
    excl = (o < excl) ? o : excl;
  }
  if (lane == 0 && excl < theta) {
    int slot = atomicAdd(fixcount, 1);
    fixlist[slot] = (int)(b * T_DIM + row);
  }
}

// ---------------- FIX kernel: recompute flagged rows exactly (fp32, ILP) ----------------
// One block per flagged row (grid-stride). Thread t owns candidates {t+256*cc},
// 8 parallel accumulators -> 16 independent 8B loads per dim-step (latency hidden
// by ILP, not occupancy). Dot order per candidate = R11-validated serial chain.
__global__ __launch_bounds__(256) void k_topk_fix(const __bf16* __restrict__ Fh,
                                                  const __bf16* __restrict__ Fl,
                                                  const float* __restrict__ sq,
                                                  const int* __restrict__ fixlist,
                                                  const int* __restrict__ fixcount,
                                                  int* __restrict__ idxo,
                                                  float* __restrict__ wo) {
  __shared__ float xr[C_DIM];
  __shared__ float difs[T_DIM];
  int n = fixcount[0];
  int tid = threadIdx.x;
  const unsigned short* fh = (const unsigned short*)Fh;
  const unsigned short* fl = (const unsigned short*)Fl;
  for (int i = blockIdx.x; i < n; i += gridDim.x) {
    int rowg = fixlist[i];
    int b = rowg >> 11, r = rowg & (T_DIM - 1);
    xr[tid] = bfbits2f(fh[(size_t)rowg * C_DIM + tid]) + bfbits2f(fl[(size_t)rowg * C_DIM + tid]);
    __syncthreads();
    const float* sqb = sq + (size_t)b * T_DIM;
    float sqi = sqb[r];
    float acc[8];
#pragma unroll
    for (int cc = 0; cc < 8; ++cc) acc[cc] = 0.f;
    const unsigned short* bh = fh + (size_t)b * T_DIM * C_DIM;
    const unsigned short* bl = fl + (size_t)b * T_DIM * C_DIM;
    for (int c4 = 0; c4 < 64; ++c4) {
      float x0 = xr[c4 * 4 + 0], x1 = xr[c4 * 4 + 1];
      float x2 = xr[c4 * 4 + 2], x3 = xr[c4 * 4 + 3];
#pragma unroll
      for (int cc = 0; cc < 8; ++cc) {
        size_t jo = (size_t)(tid + 256 * cc) * C_DIM + c4 * 4;
        ushort4 h4 = *(const ushort4*)(bh + jo);
        ushort4 l4 = *(const ushort4*)(bl + jo);
        float a = acc[cc];
        a = fmaf(bfbits2f(h4.x) + bfbits2f(l4.x), x0, a);
        a = fmaf(bfbits2f(h4.y) + bfbits2f(l4.y), x1, a);
        a = fmaf(bfbits2f(h4.z) + bfbits2f(l4.z), x2, a);
        a = fmaf(bfbits2f(h4.w) + bfbits2f(l4.w), x3, a);
        acc[cc] = a;
      }
    }
#pragma unroll
    for (int cc = 0; cc < 8; ++cc) {
      int j = tid + 256 * cc;
      difs[j] = __fmaf_rn(-2.0f, acc[cc], __fadd_rn(sqi, sqb[j]));
    }
    __syncthreads();
    if (tid < 64) {
      int lane = tid;
      u64 b0 = ~0ull, b1 = ~0ull, b2 = ~0ull, b3 = ~0ull, b4 = ~0ull,
          b5 = ~0ull, b6 = ~0ull, b7 = ~0ull, b8 = ~0ull, b9 = ~0ull;
      for (int t = 0; t < 32; ++t) {
        unsigned j = (unsigned)(lane + 64 * t);
        unsigned u = __float_as_uint(difs[j]);
        u = (u & 0x80000000u) ? ~u : (u | 0x80000000u);
        u64 key = ((u64)u << 32) | j;
        if (key < b9) {
          b9 = key;
          u64 tt;
          if (b9 < b8) { tt = b8; b8 = b9; b9 = tt; }
          if (b8 < b7) { tt = b7; b7 = b8; b8 = tt; }
          if (b7 < b6) { tt = b6; b6 = b7; b7 = tt; }
          if (b6 < b5) { tt = b5; b5 = b6; b6 = tt; }
          if (b5 < b4) { tt = b4; b4 = b5; b5 = tt; }
          if (b4 < b3) { tt = b3; b3 = b4; b4 = tt; }
          if (b3 < b2) { tt = b2; b2 = b3; b3 = tt; }
          if (b2 < b1) { tt = b1; b1 = b2; b2 = tt; }
          if (b1 < b0) { tt = b0; b0 = b1; b1 = tt; }
        }
      }
      int* idxb = idxo + (size_t)b * T_DIM * KNB;
      float* wbp = wo + (size_t)b * T_DIM * KNB;
#pragma unroll
      for (int s = 0; s < KNB; ++s) {
        u64 m = b0;
#pragma unroll
        for (int d = 1; d < 64; d <<= 1) {
          u64 o = __shfl_xor(m, d, 64);
          m = (o < m) ? o : m;
        }
        u64 bal = __ballot(b0 == m);
        int leader = (int)__builtin_ctzll(bal);
        if (lane == leader) {
          b0 = b1; b1 = b2; b2 = b3; b3 = b4; b4 = b5;
          b5 = b6; b6 = b7; b7 = b8; b8 = b9; b9 = ~0ull;
        }
        if (lane == 0) {
          int j = (int)(unsigned)(m & 0xffffffffull);
          unsigned su = (unsigned)(m >> 32);
          unsigned bits = (su & 0x80000000u) ? (su & 0x7fffffffu) : ~su;
          float dif = __uint_as_float(bits);
          float sqj = sqb[j];
          float num = 0.5f * (sqi + sqj - dif);
          float wv = num / (sqrtf(sqi) * sqrtf(sqj));
          idxb[(size_t)r * KNB + s] = j;
          wbp[(size_t)r * KNB + s] = wv;
        }
      }
    }
    __syncthreads();
  }
}

// ---------------- merged bf16 GEMM dispatch: blocks 0-3 MLP, 4-5 conv ----------------
__global__ __launch_bounds__(256, 2) void k_gemm_fused(const __bf16* __restrict__ Fh,
                                                       const __bf16* __restrict__ mlpB,
                                                       const __bf16* __restrict__ wk3,
                                                       float* __restrict__ mlpout,
                                                       float* __restrict__ convout,
                                                       const __bf16* __restrict__ zp) {
  __shared__ __bf16 As[128 * 64], Bs[128 * 64];
  int bx = blockIdx.x;
  const __bf16* Bm;
  float* C;
  int N, K, conv, n0;
  if (bx < 4) {
    Bm = mlpB; C = mlpout; N = 512; K = 256; conv = 0; n0 = bx * 128;
  } else {
    Bm = wk3; C = convout; N = 256; K = 768; conv = 1; n0 = (bx - 4) * 128;
  }
  int m0 = blockIdx.y * 128;
  int tid = threadIdx.x, w = tid >> 6, l = tid & 63;
  int wr = w >> 1, wc = w & 1;
  f32x4 acc[4][4];
#pragma unroll
  for (int i = 0; i < 4; ++i)
#pragma unroll
    for (int j = 0; j < 4; ++j) acc[i][j] = {0.f, 0.f, 0.f, 0.f};

  for (int k0 = 0; k0 < K; k0 += 64) {
    if (conv)
      stage_tile_conv(Fh, m0, k0, zp, As, w, l);
    else
      stage_tile(Fh, (size_t)m0, C_DIM, k0, As, w, l);
    stage_tile(Bm, (size_t)n0, K, k0, Bs, w, l);
    __syncthreads();
#pragma unroll
    for (int ks = 0; ks < 2; ++ks) {
      bf16x8 af[4], bf_[4];
#pragma unroll
      for (int i = 0; i < 4; ++i) af[i] = read_frag(As, wr * 4 + i, ks, l);
#pragma unroll
      for (int j = 0; j < 4; ++j) bf_[j] = read_frag(Bs, wc * 4 + j, ks, l);
#pragma unroll
      for (int i = 0; i < 4; ++i)
#pragma unroll
        for (int j = 0; j < 4; ++j)
          acc[i][j] = __builtin_amdgcn_mfma_f32_16x16x32_bf16(af[i], bf_[j], acc[i][j], 0, 0, 0);
    }
    __syncthreads();
  }
#pragma unroll
  for (int i = 0; i < 4; ++i) {
    int mrow = m0 + wr * 64 + i * 16 + ((l >> 4) << 2);
#pragma unroll
    for (int j = 0; j < 4; ++j) {
      int ncol = n0 + wc * 64 + j * 16 + (l & 15);
      float* cp = C + (size_t)mrow * N + ncol;
#pragma unroll
      for (int r = 0; r < 4; ++r) cp[(size_t)r * N] = acc[i][j][r];
    }
  }
}

// ---------------- fused gmax + conv-bias + relu + pairwise maxpool + transpose ----------------
__global__ __launch_bounds__(256) void k_gfinal(const float* __restrict__ mlpout,
                                                const float* __restrict__ mlp_b,
                                                const int* __restrict__ idxo,
                                                const float* __restrict__ wo,
                                                const float* __restrict__ convb,
                                                const float* __restrict__ cb,
                                                float* __restrict__ out) {
  __shared__ float tile[32][33];
  __shared__ int sj[64][KNB];
  __shared__ float sw[64][KNB];
  int b = blockIdx.z, c0 = blockIdx.y * 32, t20 = blockIdx.x * 32;
  int tid = threadIdx.x;
  int nbase = b * T_DIM + t20 * 2;
  for (int e = tid; e < 64 * KNB; e += 256) {
    int ln = e / KNB, k = e - ln * KNB;
    sj[ln][k] = b * T_DIM + idxo[(size_t)(nbase + ln) * KNB + k];
    sw[ln][k] = wo[(size_t)(nbase + ln) * KNB + k];
  }
  __syncthreads();
  int tx = tid & 31, ty = tid >> 5;
  int c = c0 + tx;
  float bias_c = cb[c];
  float mbias = mlp_b[c];
#pragma unroll
  for (int rr = 0; rr < 4; ++rr) {
    int lt2 = ty + 8 * rr;
    float res[2];
#pragma unroll
    for (int s = 0; s < 2; ++s) {
      int ln = 2 * lt2 + s;
      int n = nbase + ln;
      float q = mlpout[(size_t)n * 512 + 256 + c] + mbias;
      float mx = -3.4e38f;
#pragma unroll
      for (int k = 0; k < KNB; ++k) {
        float v = (mlpout[(size_t)sj[ln][k] * 512 + c] + q) * sw[ln][k];
        mx = fmaxf(mx, v);
      }
      float v = convb[(size_t)n * C_DIM + c] + mx + bias_c;
      res[s] = fmaxf(v, 0.f);
    }
    tile[lt2][tx] = fmaxf(res[0], res[1]);
  }
  __syncthreads();
#pragma unroll
  for (int rr = 0; rr < 4; ++rr) {
    int cc = c0 + ty + 8 * rr;
    out[((size_t)b * C_DIM + cc) * (T_DIM / 2) + t20 + tx] = tile[tx][ty + 8 * rr];
  }
}

// ---------------- merged repack + fixcount zeroing ----------------
__global__ void k_repack(const float* __restrict__ cw, const float* __restrict__ mw,
                         __bf16* __restrict__ wk3, __bf16* __restrict__ mlpB,
                         __bf16* __restrict__ zp, int* __restrict__ fixcount) {
  int i = blockIdx.x * 256 + threadIdx.x;
  if (i == 0) fixcount[0] = 0;
  if (i < 3 * C_DIM * C_DIM) {
    int o = i / 768;
    int rem = i - o * 768;
    int tap = rem >> 8;
    int ii = rem & 255;
    wk3[i] = bfbits(f2bf_rn(cw[(size_t)o * 768 + ii * 3 + tap]));
  } else {
    int m = i - 3 * C_DIM * C_DIM;
    if (m < 512 * 256) {
      int r = m >> 8;
      int col = m & 255;
      mlpB[m] = bfbits(f2bf_rn(mw[(size_t)(r & 255) * 512 + ((r >> 8) << 8) + col]));
    }
  }
  if (blockIdx.x == 0 && threadIdx.x < 128) zp[threadIdx.x] = bfbits(0);
}

extern "C" void kernel_launch(void* const* d_in, const int* in_sizes, int n_in,
                              void* d_out, int out_size, void* d_ws, size_t ws_size,
                              hipStream_t stream) {
  const float* x = (const float*)d_in[0];
  const float* conv_w = (const float*)d_in[2];
  const float* conv_b = (const float*)d_in[3];
  const float* mlp_w = (const float*)d_in[4];
  const float* mlp_b = (const float*)d_in[5];
  float* out = (float*)d_out;

  char* ws = (char*)d_ws;
  size_t off = 0;
  auto alloc = [&](size_t bytes) -> void* {
    void* p = ws + off;
    off += (bytes + 255) & ~(size_t)255;
    return p;
  };
  __bf16* Fh = (__bf16*)alloc((size_t)NPTS * C_DIM * 2);
  __bf16* Fl = (__bf16*)alloc((size_t)NPTS * C_DIM * 2);
  float* convout = (float*)alloc((size_t)NPTS * C_DIM * 4);
  float* mlpout = (float*)alloc((size_t)NPTS * 512 * 4);
  float* sq = (float*)alloc((size_t)NPTS * 4);
  int* idxb = (int*)alloc((size_t)NPTS * KNB * 4);
  float* wb = (float*)alloc((size_t)NPTS * KNB * 4);
  int* fixlist = (int*)alloc((size_t)NPTS * 4);
  int* fixcount = (int*)alloc(256);
  u64* kbuf = (u64*)alloc((size_t)BS * NCH * T_DIM * 12 * 8);  // 25.2 MB
  u64* bbuf = (u64*)alloc((size_t)BS * NCH * T_DIM * 8);       // 2.1 MB
  __bf16* wk3 = (__bf16*)alloc((size_t)3 * C_DIM * C_DIM * 2);
  __bf16* mlpB = (__bf16*)alloc((size_t)512 * 256 * 2);
  __bf16* zp = (__bf16*)alloc(512);

  k_repack<<<dim3(1280), 256, 0, stream>>>(conv_w, mlp_w, wk3, mlpB, zp, fixcount);
  k_transpose_split<<<dim3(T_DIM / 32, C_DIM / 32, BS), 256, 0, stream>>>(x, Fh, Fl);
  k_sq<<<dim3(NPTS / 4), 256, 0, stream>>>(Fh, Fl, sq);

  // gram tile + per-lane min-4 reduce (4096 blocks), then merge, then rare fix
  k_gram_reduce<<<dim3(NCH, T_DIM / 64, BS), 256, 0, stream>>>(Fh, Fl, sq, kbuf, bbuf);
  k_topk_merge<<<dim3(T_DIM / 4, BS), 256, 0, stream>>>(kbuf, bbuf, sq, idxb, wb, fixlist, fixcount);
  k_topk_fix<<<dim3(256), 256, 0, stream>>>(Fh, Fl, sq, fixlist, fixcount, idxb, wb);

  k_gemm_fused<<<dim3(6, NPTS / 128), 256, 0, stream>>>(Fh, mlpB, wk3, mlpout, convout, zp);

  k_gfinal<<<dim3((T_DIM / 2) / 32, C_DIM / 32, BS), 256, 0, stream>>>(
      mlpout, mlp_b, idxb, wb, convout, conv_b, out);
}

// Round 14
// 239.894 us; speedup vs baseline: 3.0023x; 1.2117x over previous
//
#include <hip/hip_runtime.h>
#include <hip/hip_bf16.h>
#include <cstdint>

#define T_DIM 2048
#define C_DIM 256
#define BS 8
#define NPTS (BS * T_DIM)
#define KNB 10
#define NCH 16   // candidate chunks of 128

typedef __bf16 bf16x8 __attribute__((ext_vector_type(8)));
typedef float f32x4 __attribute__((ext_vector_type(4)));
typedef unsigned long long u64;

#define AS1 __attribute__((address_space(1)))
#define AS3 __attribute__((address_space(3)))

__device__ __forceinline__ unsigned short f2bf_rn(float f) {
  unsigned u = __float_as_uint(f);
  unsigned r = (u + 0x7FFFu + ((u >> 16) & 1u)) >> 16;
  return (unsigned short)r;
}
__device__ __forceinline__ float bfbits2f(unsigned short h) {
  return __uint_as_float((unsigned)h << 16);
}
__device__ __forceinline__ __bf16 bfbits(unsigned short h) {
  return __builtin_bit_cast(__bf16, h);
}

// pinned dif computation: identical instruction sequence at every use site.
__device__ __forceinline__ unsigned key_hi(float sqi, float sqj, float gv) {
  float dif = __fmaf_rn(-2.0f, gv, __fadd_rn(sqi, sqj));
  unsigned u = __float_as_uint(dif);
  return (u & 0x80000000u) ? ~u : (u | 0x80000000u);
}

// ---- stage a 128x64 bf16 tile into XOR-swizzled LDS via global_load_lds ----
__device__ __forceinline__ void stage_tile(const __bf16* __restrict__ src, size_t row0,
                                           int ld, int k0, __bf16* lds, int w, int l) {
  int kofs = ((l & 7) ^ (l >> 3)) * 8;
  const __bf16* g0 = src + (row0 + (size_t)(l >> 3)) * ld + k0 + kofs;
  __bf16* lbase = lds + (size_t)(w * 4) * 512;
#pragma unroll
  for (int q4 = 0; q4 < 4; ++q4) {
    __builtin_amdgcn_global_load_lds((AS1 void*)(g0 + (size_t)(w * 4 + q4) * 8 * ld),
                                     (AS3 void*)(lbase + q4 * 512), 16, 0, 0);
  }
}

// ---- stage a 64x64 bf16 tile (row panel) ----
__device__ __forceinline__ void stage_tile64(const __bf16* __restrict__ src, size_t row0,
                                             int k0, __bf16* lds, int w, int l) {
  int kofs = ((l & 7) ^ (l >> 3)) * 8;
  const __bf16* g0 = src + (row0 + (size_t)(l >> 3)) * C_DIM + k0 + kofs;
  __bf16* lbase = lds + (size_t)(w * 2) * 512;
#pragma unroll
  for (int q4 = 0; q4 < 2; ++q4) {
    __builtin_amdgcn_global_load_lds((AS1 void*)(g0 + (size_t)(w * 2 + q4) * 8 * C_DIM),
                                     (AS3 void*)(lbase + q4 * 512), 16, 0, 0);
  }
}

// conv im2col staging: K=768 = 3 taps x 256
__device__ __forceinline__ void stage_tile_conv(const __bf16* __restrict__ src, int m0,
                                                int k0in, const __bf16* __restrict__ zp,
                                                __bf16* lds, int w, int l) {
  int tap = k0in >> 8;
  int kshift = tap - 1;
  int k0 = k0in & 255;
  int kofs = ((l & 7) ^ (l >> 3)) * 8;
  int mb = m0 & (T_DIM - 1);
#pragma unroll
  for (int q4 = 0; q4 < 4; ++q4) {
    int q = w * 4 + q4;
    int row = q * 8 + (l >> 3);
    int t = mb + row + kshift;
    const __bf16* g = ((unsigned)t < (unsigned)T_DIM)
                          ? (src + (size_t)(m0 + row + kshift) * C_DIM + k0 + kofs)
                          : (zp + kofs);
    __builtin_amdgcn_global_load_lds((AS1 void*)g, (AS3 void*)(lds + q * 512), 16, 0, 0);
  }
}

__device__ __forceinline__ bf16x8 read_frag(const __bf16* lds, int t16, int ks, int l) {
  int row = t16 * 16 + (l & 15);
  int kb = ks * 64 + ((l >> 4) << 4);
  int byte = row * 128 + (kb ^ ((row & 7) << 4));
  return *(const bf16x8*)((const char*)lds + byte);
}

// ---------------- transpose + hi/lo bf16 split ----------------
__global__ __launch_bounds__(256) void k_transpose_split(const float* __restrict__ x,
                                                         __bf16* __restrict__ Fh,
                                                         __bf16* __restrict__ Fl) {
  __shared__ float tile[32][33];
  int b = blockIdx.z;
  int t0 = blockIdx.x * 32;
  int c0 = blockIdx.y * 32;
  int tx = threadIdx.x & 31, ty = threadIdx.x >> 5;
  const float* xb = x + (size_t)b * C_DIM * T_DIM;
#pragma unroll
  for (int r = 0; r < 4; ++r) {
    int c = c0 + ty + 8 * r;
    tile[ty + 8 * r][tx] = xb[(size_t)c * T_DIM + t0 + tx];
  }
  __syncthreads();
#pragma unroll
  for (int r = 0; r < 4; ++r) {
    int t = t0 + ty + 8 * r;
    float v = tile[tx][ty + 8 * r];
    unsigned short hb = f2bf_rn(v);
    float lo = v - bfbits2f(hb);
    size_t o = ((size_t)b * T_DIM + t) * C_DIM + c0 + tx;
    Fh[o] = bfbits(hb);
    Fl[o] = bfbits(f2bf_rn(lo));
  }
}

// ---------------- sq[n] = sum_c (hi+lo)^2 ----------------
__global__ __launch_bounds__(256) void k_sq(const __bf16* __restrict__ Fh,
                                            const __bf16* __restrict__ Fl,
                                            float* __restrict__ sq) {
  int n = blockIdx.x * 4 + (threadIdx.x >> 6);
  int lane = threadIdx.x & 63;
  ushort4 hv = ((const ushort4*)Fh)[(size_t)n * 64 + lane];
  ushort4 lv = ((const ushort4*)Fl)[(size_t)n * 64 + lane];
  float s = 0.f;
  {
    float v;
    v = bfbits2f(hv.x) + bfbits2f(lv.x); s = fmaf(v, v, s);
    v = bfbits2f(hv.y) + bfbits2f(lv.y); s = fmaf(v, v, s);
    v = bfbits2f(hv.z) + bfbits2f(lv.z); s = fmaf(v, v, s);
    v = bfbits2f(hv.w) + bfbits2f(lv.w); s = fmaf(v, v, s);
  }
#pragma unroll
  for (int d = 1; d < 64; d <<= 1) s += __shfl_xor(s, d, 64);
  if (lane == 0) sq[n] = s;
}

// ---------------- gram tile + per-lane min-4 reduce (gram never hits HBM) ----------------
// Block = (chunk of 128 cands) x (panel of 64 rows) x batch. Swapped MFMA (cand=A,
// row=B) => lane l of wave w serves row w*16+(l&15); its cands = j*16+(l>>4)*4+r.
// Pass order per k identical to R10-R13 (verified): candhi*rowhi, candhi*rowlo,
// candlo*rowhi. Epilogue: exact per-lane min-4 of its 32 keys; keep 3, bound = 4th.
__global__ __launch_bounds__(256) void k_gram_reduce(const __bf16* __restrict__ Fh,
                                                     const __bf16* __restrict__ Fl,
                                                     const float* __restrict__ sq,
                                                     u64* __restrict__ kbuf,
                                                     u64* __restrict__ bbuf) {
  __shared__ __bf16 Bh[128 * 64], Bl[128 * 64];   // cand tiles (hi/lo)
  __shared__ __bf16 Rh[64 * 64], Rl[64 * 64];     // row tiles (hi/lo)
  __shared__ float sqc[128];

  int ch = blockIdx.x, p = blockIdx.y, b = blockIdx.z;
  size_t base = (size_t)b * T_DIM;
  const float* sqb = sq + base;
  int tid = threadIdx.x, w = tid >> 6, l = tid & 63, g = l >> 4;
  int r0 = p * 64;
  int cand0 = ch * 128;
  int myrow = r0 + w * 16 + (l & 15);
  float sqi = sqb[myrow];
  if (tid < 128) sqc[tid] = sqb[cand0 + tid];

  f32x4 acc[8];
#pragma unroll
  for (int j = 0; j < 8; ++j) acc[j] = {0.f, 0.f, 0.f, 0.f};

  for (int k0 = 0; k0 < C_DIM; k0 += 64) {
    stage_tile(Fh, base + cand0, C_DIM, k0, Bh, w, l);
    stage_tile(Fl, base + cand0, C_DIM, k0, Bl, w, l);
    stage_tile64(Fh, base + r0, k0, Rh, w, l);
    stage_tile64(Fl, base + r0, k0, Rl, w, l);
    __syncthreads();
#pragma unroll
    for (int ks = 0; ks < 2; ++ks) {
      bf16x8 rh = read_frag(Rh, w, ks, l);
      bf16x8 rl = read_frag(Rl, w, ks, l);
      bf16x8 cv[8];
#pragma unroll
      for (int j = 0; j < 8; ++j) cv[j] = read_frag(Bh, j, ks, l);
#pragma unroll
      for (int j = 0; j < 8; ++j)
        acc[j] = __builtin_amdgcn_mfma_f32_16x16x32_bf16(cv[j], rh, acc[j], 0, 0, 0);
#pragma unroll
      for (int j = 0; j < 8; ++j)
        acc[j] = __builtin_amdgcn_mfma_f32_16x16x32_bf16(cv[j], rl, acc[j], 0, 0, 0);
#pragma unroll
      for (int j = 0; j < 8; ++j) cv[j] = read_frag(Bl, j, ks, l);
#pragma unroll
      for (int j = 0; j < 8; ++j)
        acc[j] = __builtin_amdgcn_mfma_f32_16x16x32_bf16(cv[j], rh, acc[j], 0, 0, 0);
    }
    __syncthreads();
  }

  // exact per-lane min-4 over this lane's 32 scores
  u64 c0 = ~0ull, c1 = ~0ull, c2 = ~0ull, c3 = ~0ull;
#pragma unroll
  for (int j = 0; j < 8; ++j) {
    f32x4 sv = *(const f32x4*)&sqc[j * 16 + (g << 2)];
#pragma unroll
    for (int r = 0; r < 4; ++r) {
      unsigned u = key_hi(sqi, sv[r], acc[j][r]);
      u64 key = ((u64)u << 32) | (unsigned)(cand0 + j * 16 + (g << 2) + r);
      u64 t1 = (key > c0) ? key : c0; c0 = (key < c0) ? key : c0;
      u64 t2 = (t1 > c1) ? t1 : c1;  c1 = (t1 < c1) ? t1 : c1;
      u64 t3 = (t2 > c2) ? t2 : c2;  c2 = (t2 < c2) ? t2 : c2;
      c3 = (t3 < c3) ? t3 : c3;
    }
  }
  // keys: 3 kept per (row, chunk, quarter)
  u64* kp = kbuf + ((((size_t)b * NCH + ch) * T_DIM + myrow) * 12 + g * 3);
  kp[0] = c0;
  kp[1] = c1;
  kp[2] = c2;
  // bound: min over quarters of the 4th-smallest
  u64 bd = c3;
  { u64 o = __shfl_xor(bd, 16, 64); bd = (o < bd) ? o : bd; }
  { u64 o = __shfl_xor(bd, 32, 64); bd = (o < bd) ? o : bd; }
  if (g == 0) bbuf[((size_t)b * NCH + ch) * T_DIM + myrow] = bd;
}

// ---------------- merge: 192 kept keys/row -> top-10 + theta + flag ----------------
__global__ __launch_bounds__(256) void k_topk_merge(const u64* __restrict__ kbuf,
                                                    const u64* __restrict__ bbuf,
                                                    const float* __restrict__ sq,
                                                    int* __restrict__ idxo,
                                                    float* __restrict__ wo,
                                                    int* __restrict__ fixlist,
                                                    int* __restrict__ fixcount) {
  int b = blockIdx.y;
  int row = blockIdx.x * 4 + (threadIdx.x >> 6);
  int lane = threadIdx.x & 63;
  const float* sqb = sq + (size_t)b * T_DIM;
  float sqi = sqb[row];

  // lane covers (chunk = lane>>2, quarter = lane&3): its kept min-3
  const u64* kp = kbuf + ((((size_t)b * NCH + (lane >> 2)) * T_DIM + row) * 12 + (lane & 3) * 3);
  u64 m0 = kp[0], m1 = kp[1], m2 = kp[2];
  u64 excl = (lane < NCH) ? bbuf[((size_t)b * NCH + lane) * T_DIM + row] : ~0ull;

  // 10-round extract-min (u32 hi butterfly, then lo among hi-matching)
  u64 win[KNB];
#pragma unroll
  for (int s = 0; s < KNB; ++s) {
    unsigned mh = (unsigned)(m0 >> 32);
    unsigned h = mh;
#pragma unroll
    for (int d = 1; d < 64; d <<= 1) {
      unsigned oh = __shfl_xor(h, d, 64);
      h = (oh < h) ? oh : h;
    }
    unsigned lo = (mh == h) ? (unsigned)m0 : 0xFFFFFFFFu;
#pragma unroll
    for (int d = 1; d < 64; d <<= 1) {
      unsigned ol = __shfl_xor(lo, d, 64);
      lo = (ol < lo) ? ol : lo;
    }
    u64 m = ((u64)h << 32) | lo;
    win[s] = m;
    bool pop = (m0 == m);
    m0 = pop ? m1 : m0;
    m1 = pop ? m2 : m1;
    m2 = pop ? ~0ull : m2;
  }
  u64 theta = win[KNB - 1];

  // parallel epilogue: lane s writes winner s (output order-invariant: max over k)
  u64 mywin = win[0];
#pragma unroll
  for (int s = 1; s < KNB; ++s) mywin = (lane == s) ? win[s] : mywin;
  if (lane < KNB) {
    int j = (int)(unsigned)(mywin & 0xffffffffull);
    unsigned su = (unsigned)(mywin >> 32);
    unsigned bits = (su & 0x80000000u) ? (su & 0x7fffffffu) : ~su;
    float dif = __uint_as_float(bits);
    float sqj = sqb[j];
    float num = 0.5f * (sqi + sqj - dif);
    float wv = num / (sqrtf(sqi) * sqrtf(sqj));
    idxo[((size_t)b * T_DIM + row) * KNB + lane] = j;
    wo[((size_t)b * T_DIM + row) * KNB + lane] = wv;
  }

  // flag iff smallest excluded bound < theta
#pragma unroll
  for (int d = 1; d < 64; d <<= 1) {
    u64 o = __shfl_xor(excl, d, 64);
    excl = (o < excl) ? o : excl;
  }
  if (lane == 0 && excl < theta) {
    int slot = atomicAdd(fixcount, 1);
    fixlist[slot] = (int)(b * T_DIM + row);
  }
}

// ---------------- FIX kernel: recompute flagged rows exactly (fp32, coalesced+ILP) ----
// One block per flagged row (grid-stride). Dot phase: per wave, batches of 8
// candidates; lane l reads ushort4 at F[cand][4l] (fully coalesced 512B row-loads),
// 16 independent loads + 8 independent FMA chains + 8 interleaved butterfly reduces.
__global__ __launch_bounds__(256) void k_topk_fix(const __bf16* __restrict__ Fh,
                                                  const __bf16* __restrict__ Fl,
                                                  const float* __restrict__ sq,
                                                  const int* __restrict__ fixlist,
                                                  const int* __restrict__ fixcount,
                                                  int* __restrict__ idxo,
                                                  float* __restrict__ wo) {
  __shared__ float xr[C_DIM];
  __shared__ float difs[T_DIM];
  int n = fixcount[0];
  int tid = threadIdx.x;
  int w = tid >> 6, lane = tid & 63;
  const unsigned short* fh = (const unsigned short*)Fh;
  const unsigned short* fl = (const unsigned short*)Fl;
  for (int i = blockIdx.x; i < n; i += gridDim.x) {
    int rowg = fixlist[i];
    int b = rowg >> 11, r = rowg & (T_DIM - 1);
    xr[tid] = bfbits2f(fh[(size_t)rowg * C_DIM + tid]) + bfbits2f(fl[(size_t)rowg * C_DIM + tid]);
    __syncthreads();
    const float* sqb = sq + (size_t)b * T_DIM;
    float sqi = sqb[r];
    const unsigned short* bh = fh + (size_t)b * T_DIM * C_DIM;
    const unsigned short* bl = fl + (size_t)b * T_DIM * C_DIM;
    float x0 = xr[lane * 4 + 0], x1 = xr[lane * 4 + 1];
    float x2 = xr[lane * 4 + 2], x3 = xr[lane * 4 + 3];
    // wave w covers candidates [w*512, (w+1)*512) in 64 batches of 8
    for (int bb = 0; bb < 64; ++bb) {
      int cbase = w * 512 + bb * 8;
      float part[8];
#pragma unroll
      for (int cc = 0; cc < 8; ++cc) {
        size_t jo = (size_t)(cbase + cc) * C_DIM + lane * 4;
        ushort4 h4 = *(const ushort4*)(bh + jo);
        ushort4 l4 = *(const ushort4*)(bl + jo);
        float p = 0.f;
        p = fmaf(bfbits2f(h4.x) + bfbits2f(l4.x), x0, p);
        p = fmaf(bfbits2f(h4.y) + bfbits2f(l4.y), x1, p);
        p = fmaf(bfbits2f(h4.z) + bfbits2f(l4.z), x2, p);
        p = fmaf(bfbits2f(h4.w) + bfbits2f(l4.w), x3, p);
        part[cc] = p;
      }
#pragma unroll
      for (int d = 1; d < 64; d <<= 1) {
#pragma unroll
        for (int cc = 0; cc < 8; ++cc) part[cc] += __shfl_xor(part[cc], d, 64);
      }
      // lane cc writes candidate cbase+cc (static select, rule #20)
      float myp = part[0];
#pragma unroll
      for (int cc = 1; cc < 8; ++cc) myp = (lane == cc) ? part[cc] : myp;
      if (lane < 8) {
        int j = cbase + lane;
        difs[j] = __fmaf_rn(-2.0f, myp, __fadd_rn(sqi, sqb[j]));
      }
    }
    __syncthreads();
    if (tid < 64) {
      u64 b0 = ~0ull, b1 = ~0ull, b2 = ~0ull, b3 = ~0ull, b4 = ~0ull,
          b5 = ~0ull, b6 = ~0ull, b7 = ~0ull, b8 = ~0ull, b9 = ~0ull;
      for (int t = 0; t < 32; ++t) {
        unsigned j = (unsigned)(lane + 64 * t);
        unsigned u = __float_as_uint(difs[j]);
        u = (u & 0x80000000u) ? ~u : (u | 0x80000000u);
        u64 key = ((u64)u << 32) | j;
        if (key < b9) {
          b9 = key;
          u64 tt;
          if (b9 < b8) { tt = b8; b8 = b9; b9 = tt; }
          if (b8 < b7) { tt = b7; b7 = b8; b8 = tt; }
          if (b7 < b6) { tt = b6; b6 = b7; b7 = tt; }
          if (b6 < b5) { tt = b5; b5 = b6; b6 = tt; }
          if (b5 < b4) { tt = b4; b4 = b5; b5 = tt; }
          if (b4 < b3) { tt = b3; b3 = b4; b4 = tt; }
          if (b3 < b2) { tt = b2; b2 = b3; b3 = tt; }
          if (b2 < b1) { tt = b1; b1 = b2; b2 = tt; }
          if (b1 < b0) { tt = b0; b0 = b1; b1 = tt; }
        }
      }
      int* idxb = idxo + (size_t)b * T_DIM * KNB;
      float* wbp = wo + (size_t)b * T_DIM * KNB;
#pragma unroll
      for (int s = 0; s < KNB; ++s) {
        u64 m = b0;
#pragma unroll
        for (int d = 1; d < 64; d <<= 1) {
          u64 o = __shfl_xor(m, d, 64);
          m = (o < m) ? o : m;
        }
        u64 bal = __ballot(b0 == m);
        int leader = (int)__builtin_ctzll(bal);
        if (lane == leader) {
          b0 = b1; b1 = b2; b2 = b3; b3 = b4; b4 = b5;
          b5 = b6; b6 = b7; b7 = b8; b8 = b9; b9 = ~0ull;
        }
        if (lane == 0) {
          int j = (int)(unsigned)(m & 0xffffffffull);
          unsigned su = (unsigned)(m >> 32);
          unsigned bits = (su & 0x80000000u) ? (su & 0x7fffffffu) : ~su;
          float dif = __uint_as_float(bits);
          float sqj = sqb[j];
          float num = 0.5f * (sqi + sqj - dif);
          float wv = num / (sqrtf(sqi) * sqrtf(sqj));
          idxb[(size_t)r * KNB + s] = j;
          wbp[(size_t)r * KNB + s] = wv;
        }
      }
    }
    __syncthreads();
  }
}

// ---------------- merged bf16 GEMM dispatch: blocks 0-3 MLP, 4-5 conv ----------------
__global__ __launch_bounds__(256, 2) void k_gemm_fused(const __bf16* __restrict__ Fh,
                                                       const __bf16* __restrict__ mlpB,
                                                       const __bf16* __restrict__ wk3,
                                                       float* __restrict__ mlpout,
                                                       float* __restrict__ convout,
                                                       const __bf16* __restrict__ zp) {
  __shared__ __bf16 As[128 * 64], Bs[128 * 64];
  int bx = blockIdx.x;
  const __bf16* Bm;
  float* C;
  int N, K, conv, n0;
  if (bx < 4) {
    Bm = mlpB; C = mlpout; N = 512; K = 256; conv = 0; n0 = bx * 128;
  } else {
    Bm = wk3; C = convout; N = 256; K = 768; conv = 1; n0 = (bx - 4) * 128;
  }
  int m0 = blockIdx.y * 128;
  int tid = threadIdx.x, w = tid >> 6, l = tid & 63;
  int wr = w >> 1, wc = w & 1;
  f32x4 acc[4][4];
#pragma unroll
  for (int i = 0; i < 4; ++i)
#pragma unroll
    for (int j = 0; j < 4; ++j) acc[i][j] = {0.f, 0.f, 0.f, 0.f};

  for (int k0 = 0; k0 < K; k0 += 64) {
    if (conv)
      stage_tile_conv(Fh, m0, k0, zp, As, w, l);
    else
      stage_tile(Fh, (size_t)m0, C_DIM, k0, As, w, l);
    stage_tile(Bm, (size_t)n0, K, k0, Bs, w, l);
    __syncthreads();
#pragma unroll
    for (int ks = 0; ks < 2; ++ks) {
      bf16x8 af[4], bf_[4];
#pragma unroll
      for (int i = 0; i < 4; ++i) af[i] = read_frag(As, wr * 4 + i, ks, l);
#pragma unroll
      for (int j = 0; j < 4; ++j) bf_[j] = read_frag(Bs, wc * 4 + j, ks, l);
#pragma unroll
      for (int i = 0; i < 4; ++i)
#pragma unroll
        for (int j = 0; j < 4; ++j)
          acc[i][j] = __builtin_amdgcn_mfma_f32_16x16x32_bf16(af[i], bf_[j], acc[i][j], 0, 0, 0);
    }
    __syncthreads();
  }
#pragma unroll
  for (int i = 0; i < 4; ++i) {
    int mrow = m0 + wr * 64 + i * 16 + ((l >> 4) << 2);
#pragma unroll
    for (int j = 0; j < 4; ++j) {
      int ncol = n0 + wc * 64 + j * 16 + (l & 15);
      float* cp = C + (size_t)mrow * N + ncol;
#pragma unroll
      for (int r = 0; r < 4; ++r) cp[(size_t)r * N] = acc[i][j][r];
    }
  }
}

// ---------------- fused gmax + conv-bias + relu + pairwise maxpool + transpose ----------------
__global__ __launch_bounds__(256) void k_gfinal(const float* __restrict__ mlpout,
                                                const float* __restrict__ mlp_b,
                                                const int* __restrict__ idxo,
                                                const float* __restrict__ wo,
                                                const float* __restrict__ convb,
                                                const float* __restrict__ cb,
                                                float* __restrict__ out) {
  __shared__ float tile[32][33];
  __shared__ int sj[64][KNB];
  __shared__ float sw[64][KNB];
  int b = blockIdx.z, c0 = blockIdx.y * 32, t20 = blockIdx.x * 32;
  int tid = threadIdx.x;
  int nbase = b * T_DIM + t20 * 2;
  for (int e = tid; e < 64 * KNB; e += 256) {
    int ln = e / KNB, k = e - ln * KNB;
    sj[ln][k] = b * T_DIM + idxo[(size_t)(nbase + ln) * KNB + k];
    sw[ln][k] = wo[(size_t)(nbase + ln) * KNB + k];
  }
  __syncthreads();
  int tx = tid & 31, ty = tid >> 5;
  int c = c0 + tx;
  float bias_c = cb[c];
  float mbias = mlp_b[c];
#pragma unroll
  for (int rr = 0; rr < 4; ++rr) {
    int lt2 = ty + 8 * rr;
    float res[2];
#pragma unroll
    for (int s = 0; s < 2; ++s) {
      int ln = 2 * lt2 + s;
      int n = nbase + ln;
      float q = mlpout[(size_t)n * 512 + 256 + c] + mbias;
      float mx = -3.4e38f;
#pragma unroll
      for (int k = 0; k < KNB; ++k) {
        float v = (mlpout[(size_t)sj[ln][k] * 512 + c] + q) * sw[ln][k];
        mx = fmaxf(mx, v);
      }
      float v = convb[(size_t)n * C_DIM + c] + mx + bias_c;
      res[s] = fmaxf(v, 0.f);
    }
    tile[lt2][tx] = fmaxf(res[0], res[1]);
  }
  __syncthreads();
#pragma unroll
  for (int rr = 0; rr < 4; ++rr) {
    int cc = c0 + ty + 8 * rr;
    out[((size_t)b * C_DIM + cc) * (T_DIM / 2) + t20 + tx] = tile[tx][ty + 8 * rr];
  }
}

// ---------------- merged repack + fixcount zeroing ----------------
__global__ void k_repack(const float* __restrict__ cw, const float* __restrict__ mw,
                         __bf16* __restrict__ wk3, __bf16* __restrict__ mlpB,
                         __bf16* __restrict__ zp, int* __restrict__ fixcount) {
  int i = blockIdx.x * 256 + threadIdx.x;
  if (i == 0) fixcount[0] = 0;
  if (i < 3 * C_DIM * C_DIM) {
    int o = i / 768;
    int rem = i - o * 768;
    int tap = rem >> 8;
    int ii = rem & 255;
    wk3[i] = bfbits(f2bf_rn(cw[(size_t)o * 768 + ii * 3 + tap]));
  } else {
    int m = i - 3 * C_DIM * C_DIM;
    if (m < 512 * 256) {
      int r = m >> 8;
      int col = m & 255;
      mlpB[m] = bfbits(f2bf_rn(mw[(size_t)(r & 255) * 512 + ((r >> 8) << 8) + col]));
    }
  }
  if (blockIdx.x == 0 && threadIdx.x < 128) zp[threadIdx.x] = bfbits(0);
}

extern "C" void kernel_launch(void* const* d_in, const int* in_sizes, int n_in,
                              void* d_out, int out_size, void* d_ws, size_t ws_size,
                              hipStream_t stream) {
  const float* x = (const float*)d_in[0];
  const float* conv_w = (const float*)d_in[2];
  const float* conv_b = (const float*)d_in[3];
  const float* mlp_w = (const float*)d_in[4];
  const float* mlp_b = (const float*)d_in[5];
  float* out = (float*)d_out;

  char* ws = (char*)d_ws;
  size_t off = 0;
  auto alloc = [&](size_t bytes) -> void* {
    void* p = ws + off;
    off += (bytes + 255) & ~(size_t)255;
    return p;
  };
  __bf16* Fh = (__bf16*)alloc((size_t)NPTS * C_DIM * 2);
  __bf16* Fl = (__bf16*)alloc((size_t)NPTS * C_DIM * 2);
  float* convout = (float*)alloc((size_t)NPTS * C_DIM * 4);
  float* mlpout = (float*)alloc((size_t)NPTS * 512 * 4);
  float* sq = (float*)alloc((size_t)NPTS * 4);
  int* idxb = (int*)alloc((size_t)NPTS * KNB * 4);
  float* wb = (float*)alloc((size_t)NPTS * KNB * 4);
  int* fixlist = (int*)alloc((size_t)NPTS * 4);
  int* fixcount = (int*)alloc(256);
  u64* kbuf = (u64*)alloc((size_t)BS * NCH * T_DIM * 12 * 8);  // 25.2 MB
  u64* bbuf = (u64*)alloc((size_t)BS * NCH * T_DIM * 8);       // 2.1 MB
  __bf16* wk3 = (__bf16*)alloc((size_t)3 * C_DIM * C_DIM * 2);
  __bf16* mlpB = (__bf16*)alloc((size_t)512 * 256 * 2);
  __bf16* zp = (__bf16*)alloc(512);

  k_repack<<<dim3(1280), 256, 0, stream>>>(conv_w, mlp_w, wk3, mlpB, zp, fixcount);
  k_transpose_split<<<dim3(T_DIM / 32, C_DIM / 32, BS), 256, 0, stream>>>(x, Fh, Fl);
  k_sq<<<dim3(NPTS / 4), 256, 0, stream>>>(Fh, Fl, sq);

  // gram tile + per-lane min-4 reduce (4096 blocks), then merge, then rare fix
  k_gram_reduce<<<dim3(NCH, T_DIM / 64, BS), 256, 0, stream>>>(Fh, Fl, sq, kbuf, bbuf);
  k_topk_merge<<<dim3(T_DIM / 4, BS), 256, 0, stream>>>(kbuf, bbuf, sq, idxb, wb, fixlist, fixcount);
  k_topk_fix<<<dim3(256), 256, 0, stream>>>(Fh, Fl, sq, fixlist, fixcount, idxb, wb);

  k_gemm_fused<<<dim3(6, NPTS / 128), 256, 0, stream>>>(Fh, mlpB, wk3, mlpout, convout, zp);

  k_gfinal<<<dim3((T_DIM / 2) / 32, C_DIM / 32, BS), 256, 0, stream>>>(
      mlpout, mlp_b, idxb, wb, convout, conv_b, out);
}

// Round 15
// 166.998 us; speedup vs baseline: 4.3128x; 1.4365x over previous
//
#include <hip/hip_runtime.h>
#include <hip/hip_bf16.h>
#include <cstdint>

#define T_DIM 2048
#define C_DIM 256
#define BS 8
#define NPTS (BS * T_DIM)
#define KNB 10
#define NCH 16   // candidate chunks of 128

typedef __bf16 bf16x8 __attribute__((ext_vector_type(8)));
typedef float f32x4 __attribute__((ext_vector_type(4)));
typedef unsigned long long u64;

#define AS1 __attribute__((address_space(1)))
#define AS3 __attribute__((address_space(3)))

__device__ __forceinline__ unsigned short f2bf_rn(float f) {
  unsigned u = __float_as_uint(f);
  unsigned r = (u + 0x7FFFu + ((u >> 16) & 1u)) >> 16;
  return (unsigned short)r;
}
__device__ __forceinline__ float bfbits2f(unsigned short h) {
  return __uint_as_float((unsigned)h << 16);
}
__device__ __forceinline__ __bf16 bfbits(unsigned short h) {
  return __builtin_bit_cast(__bf16, h);
}

// pinned dif computation: identical instruction sequence at every use site.
__device__ __forceinline__ unsigned key_hi(float sqi, float sqj, float gv) {
  float dif = __fmaf_rn(-2.0f, gv, __fadd_rn(sqi, sqj));
  unsigned u = __float_as_uint(dif);
  return (u & 0x80000000u) ? ~u : (u | 0x80000000u);
}
__device__ __forceinline__ unsigned flip32(float dif) {
  unsigned u = __float_as_uint(dif);
  return (u & 0x80000000u) ? ~u : (u | 0x80000000u);
}

// ---- stage a 128x64 bf16 tile into XOR-swizzled LDS via global_load_lds ----
__device__ __forceinline__ void stage_tile(const __bf16* __restrict__ src, size_t row0,
                                           int ld, int k0, __bf16* lds, int w, int l) {
  int kofs = ((l & 7) ^ (l >> 3)) * 8;
  const __bf16* g0 = src + (row0 + (size_t)(l >> 3)) * ld + k0 + kofs;
  __bf16* lbase = lds + (size_t)(w * 4) * 512;
#pragma unroll
  for (int q4 = 0; q4 < 4; ++q4) {
    __builtin_amdgcn_global_load_lds((AS1 void*)(g0 + (size_t)(w * 4 + q4) * 8 * ld),
                                     (AS3 void*)(lbase + q4 * 512), 16, 0, 0);
  }
}

// ---- stage a 64x64 bf16 tile (row panel) ----
__device__ __forceinline__ void stage_tile64(const __bf16* __restrict__ src, size_t row0,
                                             int k0, __bf16* lds, int w, int l) {
  int kofs = ((l & 7) ^ (l >> 3)) * 8;
  const __bf16* g0 = src + (row0 + (size_t)(l >> 3)) * C_DIM + k0 + kofs;
  __bf16* lbase = lds + (size_t)(w * 2) * 512;
#pragma unroll
  for (int q4 = 0; q4 < 2; ++q4) {
    __builtin_amdgcn_global_load_lds((AS1 void*)(g0 + (size_t)(w * 2 + q4) * 8 * C_DIM),
                                     (AS3 void*)(lbase + q4 * 512), 16, 0, 0);
  }
}

// conv im2col staging: K=768 = 3 taps x 256
__device__ __forceinline__ void stage_tile_conv(const __bf16* __restrict__ src, int m0,
                                                int k0in, const __bf16* __restrict__ zp,
                                                __bf16* lds, int w, int l) {
  int tap = k0in >> 8;
  int kshift = tap - 1;
  int k0 = k0in & 255;
  int kofs = ((l & 7) ^ (l >> 3)) * 8;
  int mb = m0 & (T_DIM - 1);
#pragma unroll
  for (int q4 = 0; q4 < 4; ++q4) {
    int q = w * 4 + q4;
    int row = q * 8 + (l >> 3);
    int t = mb + row + kshift;
    const __bf16* g = ((unsigned)t < (unsigned)T_DIM)
                          ? (src + (size_t)(m0 + row + kshift) * C_DIM + k0 + kofs)
                          : (zp + kofs);
    __builtin_amdgcn_global_load_lds((AS1 void*)g, (AS3 void*)(lds + q * 512), 16, 0, 0);
  }
}

__device__ __forceinline__ bf16x8 read_frag(const __bf16* lds, int t16, int ks, int l) {
  int row = t16 * 16 + (l & 15);
  int kb = ks * 64 + ((l >> 4) << 4);
  int byte = row * 128 + (kb ^ ((row & 7) << 4));
  return *(const bf16x8*)((const char*)lds + byte);
}

// ---------------- transpose + hi/lo bf16 split ----------------
__global__ __launch_bounds__(256) void k_transpose_split(const float* __restrict__ x,
                                                         __bf16* __restrict__ Fh,
                                                         __bf16* __restrict__ Fl) {
  __shared__ float tile[32][33];
  int b = blockIdx.z;
  int t0 = blockIdx.x * 32;
  int c0 = blockIdx.y * 32;
  int tx = threadIdx.x & 31, ty = threadIdx.x >> 5;
  const float* xb = x + (size_t)b * C_DIM * T_DIM;
#pragma unroll
  for (int r = 0; r < 4; ++r) {
    int c = c0 + ty + 8 * r;
    tile[ty + 8 * r][tx] = xb[(size_t)c * T_DIM + t0 + tx];
  }
  __syncthreads();
#pragma unroll
  for (int r = 0; r < 4; ++r) {
    int t = t0 + ty + 8 * r;
    float v = tile[tx][ty + 8 * r];
    unsigned short hb = f2bf_rn(v);
    float lo = v - bfbits2f(hb);
    size_t o = ((size_t)b * T_DIM + t) * C_DIM + c0 + tx;
    Fh[o] = bfbits(hb);
    Fl[o] = bfbits(f2bf_rn(lo));
  }
}

// ---------------- sq[n] = sum_c (hi+lo)^2 ----------------
__global__ __launch_bounds__(256) void k_sq(const __bf16* __restrict__ Fh,
                                            const __bf16* __restrict__ Fl,
                                            float* __restrict__ sq) {
  int n = blockIdx.x * 4 + (threadIdx.x >> 6);
  int lane = threadIdx.x & 63;
  ushort4 hv = ((const ushort4*)Fh)[(size_t)n * 64 + lane];
  ushort4 lv = ((const ushort4*)Fl)[(size_t)n * 64 + lane];
  float s = 0.f;
  {
    float v;
    v = bfbits2f(hv.x) + bfbits2f(lv.x); s = fmaf(v, v, s);
    v = bfbits2f(hv.y) + bfbits2f(lv.y); s = fmaf(v, v, s);
    v = bfbits2f(hv.z) + bfbits2f(lv.z); s = fmaf(v, v, s);
    v = bfbits2f(hv.w) + bfbits2f(lv.w); s = fmaf(v, v, s);
  }
#pragma unroll
  for (int d = 1; d < 64; d <<= 1) s += __shfl_xor(s, d, 64);
  if (lane == 0) sq[n] = s;
}

// ---------------- gram tile + per-lane min-4 reduce (gram never hits HBM) ----------------
__global__ __launch_bounds__(256) void k_gram_reduce(const __bf16* __restrict__ Fh,
                                                     const __bf16* __restrict__ Fl,
                                                     const float* __restrict__ sq,
                                                     u64* __restrict__ kbuf,
                                                     u64* __restrict__ bbuf) {
  __shared__ __bf16 Bh[128 * 64], Bl[128 * 64];   // cand tiles (hi/lo)
  __shared__ __bf16 Rh[64 * 64], Rl[64 * 64];     // row tiles (hi/lo)
  __shared__ float sqc[128];

  int ch = blockIdx.x, p = blockIdx.y, b = blockIdx.z;
  size_t base = (size_t)b * T_DIM;
  const float* sqb = sq + base;
  int tid = threadIdx.x, w = tid >> 6, l = tid & 63, g = l >> 4;
  int r0 = p * 64;
  int cand0 = ch * 128;
  int myrow = r0 + w * 16 + (l & 15);
  float sqi = sqb[myrow];
  if (tid < 128) sqc[tid] = sqb[cand0 + tid];

  f32x4 acc[8];
#pragma unroll
  for (int j = 0; j < 8; ++j) acc[j] = {0.f, 0.f, 0.f, 0.f};

  for (int k0 = 0; k0 < C_DIM; k0 += 64) {
    stage_tile(Fh, base + cand0, C_DIM, k0, Bh, w, l);
    stage_tile(Fl, base + cand0, C_DIM, k0, Bl, w, l);
    stage_tile64(Fh, base + r0, k0, Rh, w, l);
    stage_tile64(Fl, base + r0, k0, Rl, w, l);
    __syncthreads();
#pragma unroll
    for (int ks = 0; ks < 2; ++ks) {
      bf16x8 rh = read_frag(Rh, w, ks, l);
      bf16x8 rl = read_frag(Rl, w, ks, l);
      bf16x8 cv[8];
#pragma unroll
      for (int j = 0; j < 8; ++j) cv[j] = read_frag(Bh, j, ks, l);
#pragma unroll
      for (int j = 0; j < 8; ++j)
        acc[j] = __builtin_amdgcn_mfma_f32_16x16x32_bf16(cv[j], rh, acc[j], 0, 0, 0);
#pragma unroll
      for (int j = 0; j < 8; ++j)
        acc[j] = __builtin_amdgcn_mfma_f32_16x16x32_bf16(cv[j], rl, acc[j], 0, 0, 0);
#pragma unroll
      for (int j = 0; j < 8; ++j) cv[j] = read_frag(Bl, j, ks, l);
#pragma unroll
      for (int j = 0; j < 8; ++j)
        acc[j] = __builtin_amdgcn_mfma_f32_16x16x32_bf16(cv[j], rh, acc[j], 0, 0, 0);
    }
    __syncthreads();
  }

  // exact per-lane min-4 over this lane's 32 scores
  u64 c0 = ~0ull, c1 = ~0ull, c2 = ~0ull, c3 = ~0ull;
#pragma unroll
  for (int j = 0; j < 8; ++j) {
    f32x4 sv = *(const f32x4*)&sqc[j * 16 + (g << 2)];
#pragma unroll
    for (int r = 0; r < 4; ++r) {
      unsigned u = key_hi(sqi, sv[r], acc[j][r]);
      u64 key = ((u64)u << 32) | (unsigned)(cand0 + j * 16 + (g << 2) + r);
      u64 t1 = (key > c0) ? key : c0; c0 = (key < c0) ? key : c0;
      u64 t2 = (t1 > c1) ? t1 : c1;  c1 = (t1 < c1) ? t1 : c1;
      u64 t3 = (t2 > c2) ? t2 : c2;  c2 = (t2 < c2) ? t2 : c2;
      c3 = (t3 < c3) ? t3 : c3;
    }
  }
  u64* kp = kbuf + ((((size_t)b * NCH + ch) * T_DIM + myrow) * 12 + g * 3);
  kp[0] = c0;
  kp[1] = c1;
  kp[2] = c2;
  u64 bd = c3;
  { u64 o = __shfl_xor(bd, 16, 64); bd = (o < bd) ? o : bd; }
  { u64 o = __shfl_xor(bd, 32, 64); bd = (o < bd) ? o : bd; }
  if (g == 0) bbuf[((size_t)b * NCH + ch) * T_DIM + myrow] = bd;
}

// ---------------- merge: 192 kept keys/row -> top-10 + theta + flag ----------------
__global__ __launch_bounds__(256) void k_topk_merge(const u64* __restrict__ kbuf,
                                                    const u64* __restrict__ bbuf,
                                                    const float* __restrict__ sq,
                                                    int* __restrict__ idxo,
                                                    float* __restrict__ wo,
                                                    int* __restrict__ fixlist,
                                                    int* __restrict__ fixcount) {
  int b = blockIdx.y;
  int row = blockIdx.x * 4 + (threadIdx.x >> 6);
  int lane = threadIdx.x & 63;
  const float* sqb = sq + (size_t)b * T_DIM;
  float sqi = sqb[row];

  const u64* kp = kbuf + ((((size_t)b * NCH + (lane >> 2)) * T_DIM + row) * 12 + (lane & 3) * 3);
  u64 m0 = kp[0], m1 = kp[1], m2 = kp[2];
  u64 excl = (lane < NCH) ? bbuf[((size_t)b * NCH + lane) * T_DIM + row] : ~0ull;

  u64 win[KNB];
#pragma unroll
  for (int s = 0; s < KNB; ++s) {
    unsigned mh = (unsigned)(m0 >> 32);
    unsigned h = mh;
#pragma unroll
    for (int d = 1; d < 64; d <<= 1) {
      unsigned oh = __shfl_xor(h, d, 64);
      h = (oh < h) ? oh : h;
    }
    unsigned lo = (mh == h) ? (unsigned)m0 : 0xFFFFFFFFu;
#pragma unroll
    for (int d = 1; d < 64; d <<= 1) {
      unsigned ol = __shfl_xor(lo, d, 64);
      lo = (ol < lo) ? ol : lo;
    }
    u64 m = ((u64)h << 32) | lo;
    win[s] = m;
    bool pop = (m0 == m);
    m0 = pop ? m1 : m0;
    m1 = pop ? m2 : m1;
    m2 = pop ? ~0ull : m2;
  }
  u64 theta = win[KNB - 1];

  u64 mywin = win[0];
#pragma unroll
  for (int s = 1; s < KNB; ++s) mywin = (lane == s) ? win[s] : mywin;
  if (lane < KNB) {
    int j = (int)(unsigned)(mywin & 0xffffffffull);
    unsigned su = (unsigned)(mywin >> 32);
    unsigned bits = (su & 0x80000000u) ? (su & 0x7fffffffu) : ~su;
    float dif = __uint_as_float(bits);
    float sqj = sqb[j];
    float num = 0.5f * (sqi + sqj - dif);
    float wv = num / (sqrtf(sqi) * sqrtf(sqj));
    idxo[((size_t)b * T_DIM + row) * KNB + lane] = j;
    wo[((size_t)b * T_DIM + row) * KNB + lane] = wv;
  }

#pragma unroll
  for (int d = 1; d < 64; d <<= 1) {
    u64 o = __shfl_xor(excl, d, 64);
    excl = (o < excl) ? o : excl;
  }
  if (lane == 0 && excl < theta) {
    int slot = atomicAdd(fixcount, 1);
    fixlist[slot] = (int)(b * T_DIM + row);
  }
}

// ---------------- FIX phase A: per (row, 64-cand chunk) exact dots + chunk top-10 ----
// grid (32, 64): block (q, i-stride). 4 threads per candidate (quarter dims each),
// 2-step shfl reduce, then one wave extracts the chunk's top-10 -> kpart[i][q][10].
__global__ __launch_bounds__(256) void k_fix_dots(const __bf16* __restrict__ Fh,
                                                  const __bf16* __restrict__ Fl,
                                                  const float* __restrict__ sq,
                                                  const int* __restrict__ fixlist,
                                                  const int* __restrict__ fixcount,
                                                  u64* __restrict__ kpart) {
  __shared__ float xr[C_DIM];
  __shared__ float difs[64];
  int n = fixcount[0];
  int q = blockIdx.x;
  int tid = threadIdx.x;
  const unsigned short* fh = (const unsigned short*)Fh;
  const unsigned short* fl = (const unsigned short*)Fl;
  for (int i = blockIdx.y; i < n; i += gridDim.y) {
    int rowg = fixlist[i];
    int b = rowg >> 11, r = rowg & (T_DIM - 1);
    xr[tid] = bfbits2f(fh[(size_t)rowg * C_DIM + tid]) + bfbits2f(fl[(size_t)rowg * C_DIM + tid]);
    __syncthreads();
    const float* sqb = sq + (size_t)b * T_DIM;
    float sqi = sqb[r];
    int cand = q * 64 + (tid >> 2);
    int qd = tid & 3;
    size_t jo = ((size_t)b * T_DIM + cand) * C_DIM + qd * 64;
    float p = 0.f;
#pragma unroll 4
    for (int k = 0; k < 16; ++k) {
      ushort4 h4 = *(const ushort4*)(fh + jo + k * 4);
      ushort4 l4 = *(const ushort4*)(fl + jo + k * 4);
      int xb_ = qd * 64 + k * 4;
      p = fmaf(bfbits2f(h4.x) + bfbits2f(l4.x), xr[xb_ + 0], p);
      p = fmaf(bfbits2f(h4.y) + bfbits2f(l4.y), xr[xb_ + 1], p);
      p = fmaf(bfbits2f(h4.z) + bfbits2f(l4.z), xr[xb_ + 2], p);
      p = fmaf(bfbits2f(h4.w) + bfbits2f(l4.w), xr[xb_ + 3], p);
    }
    p += __shfl_xor(p, 1, 64);
    p += __shfl_xor(p, 2, 64);
    if (qd == 0) difs[tid >> 2] = __fmaf_rn(-2.0f, p, __fadd_rn(sqi, sqb[cand]));
    __syncthreads();
    if (tid < 64) {
      int lane = tid;
      u64 key = ((u64)flip32(difs[lane]) << 32) | (unsigned)(q * 64 + lane);
      u64 mywin = ~0ull;
#pragma unroll
      for (int s = 0; s < KNB; ++s) {
        u64 m = key;
#pragma unroll
        for (int d = 1; d < 64; d <<= 1) {
          u64 o = __shfl_xor(m, d, 64);
          m = (o < m) ? o : m;
        }
        if (key == m) key = ~0ull;           // pop winner (indices distinct)
        mywin = (lane == s) ? m : mywin;
      }
      if (lane < KNB) kpart[((size_t)i * 32 + q) * KNB + lane] = mywin;
    }
    __syncthreads();
  }
}

// ---------------- FIX phase B: merge 32x10 chunk keys -> final top-10 per row ----
__global__ __launch_bounds__(256) void k_fix_merge(const float* __restrict__ sq,
                                                   const int* __restrict__ fixlist,
                                                   const int* __restrict__ fixcount,
                                                   const u64* __restrict__ kpart,
                                                   int* __restrict__ idxo,
                                                   float* __restrict__ wo) {
  int n = fixcount[0];
  int w = threadIdx.x >> 6, lane = threadIdx.x & 63;
  for (int i = blockIdx.x * 4 + w; i < n; i += gridDim.x * 4) {
    int rowg = fixlist[i];
    int b = rowg >> 11, r = rowg & (T_DIM - 1);
    const float* sqb = sq + (size_t)b * T_DIM;
    float sqi = sqb[r];
    const u64* kp = kpart + (size_t)i * 320;
    // 5 keys per lane (coalesced), sorted ascending s0..s4
    u64 s0 = kp[lane], s1 = ~0ull, s2 = ~0ull, s3 = ~0ull, s4 = ~0ull;
#pragma unroll
    for (int t = 1; t < 5; ++t) {
      u64 k = kp[lane + 64 * t];
      u64 hi;
      hi = (k > s0) ? k : s0; s0 = (k < s0) ? k : s0; k = hi;
      hi = (k > s1) ? k : s1; s1 = (k < s1) ? k : s1; k = hi;
      hi = (k > s2) ? k : s2; s2 = (k < s2) ? k : s2; k = hi;
      hi = (k > s3) ? k : s3; s3 = (k < s3) ? k : s3; k = hi;
      s4 = (k < s4) ? k : s4;
    }
    u64 mywin = ~0ull;
#pragma unroll
    for (int s = 0; s < KNB; ++s) {
      u64 m = s0;
#pragma unroll
      for (int d = 1; d < 64; d <<= 1) {
        u64 o = __shfl_xor(m, d, 64);
        m = (o < m) ? o : m;
      }
      bool pop = (s0 == m);
      s0 = pop ? s1 : s0; s1 = pop ? s2 : s1; s2 = pop ? s3 : s2;
      s3 = pop ? s4 : s3; s4 = pop ? ~0ull : s4;
      mywin = (lane == s) ? m : mywin;
    }
    if (lane < KNB) {
      int j = (int)(unsigned)(mywin & 0xffffffffull);
      unsigned su = (unsigned)(mywin >> 32);
      unsigned bits = (su & 0x80000000u) ? (su & 0x7fffffffu) : ~su;
      float dif = __uint_as_float(bits);
      float sqj = sqb[j];
      float num = 0.5f * (sqi + sqj - dif);
      float wv = num / (sqrtf(sqi) * sqrtf(sqj));
      idxo[((size_t)b * T_DIM + r) * KNB + lane] = j;
      wo[((size_t)b * T_DIM + r) * KNB + lane] = wv;
    }
  }
}

// ---------------- merged bf16 GEMM dispatch: blocks 0-3 MLP, 4-5 conv ----------------
__global__ __launch_bounds__(256, 2) void k_gemm_fused(const __bf16* __restrict__ Fh,
                                                       const __bf16* __restrict__ mlpB,
                                                       const __bf16* __restrict__ wk3,
                                                       float* __restrict__ mlpout,
                                                       float* __restrict__ convout,
                                                       const __bf16* __restrict__ zp) {
  __shared__ __bf16 As[128 * 64], Bs[128 * 64];
  int bx = blockIdx.x;
  const __bf16* Bm;
  float* C;
  int N, K, conv, n0;
  if (bx < 4) {
    Bm = mlpB; C = mlpout; N = 512; K = 256; conv = 0; n0 = bx * 128;
  } else {
    Bm = wk3; C = convout; N = 256; K = 768; conv = 1; n0 = (bx - 4) * 128;
  }
  int m0 = blockIdx.y * 128;
  int tid = threadIdx.x, w = tid >> 6, l = tid & 63;
  int wr = w >> 1, wc = w & 1;
  f32x4 acc[4][4];
#pragma unroll
  for (int i = 0; i < 4; ++i)
#pragma unroll
    for (int j = 0; j < 4; ++j) acc[i][j] = {0.f, 0.f, 0.f, 0.f};

  for (int k0 = 0; k0 < K; k0 += 64) {
    if (conv)
      stage_tile_conv(Fh, m0, k0, zp, As, w, l);
    else
      stage_tile(Fh, (size_t)m0, C_DIM, k0, As, w, l);
    stage_tile(Bm, (size_t)n0, K, k0, Bs, w, l);
    __syncthreads();
#pragma unroll
    for (int ks = 0; ks < 2; ++ks) {
      bf16x8 af[4], bf_[4];
#pragma unroll
      for (int i = 0; i < 4; ++i) af[i] = read_frag(As, wr * 4 + i, ks, l);
#pragma unroll
      for (int j = 0; j < 4; ++j) bf_[j] = read_frag(Bs, wc * 4 + j, ks, l);
#pragma unroll
      for (int i = 0; i < 4; ++i)
#pragma unroll
        for (int j = 0; j < 4; ++j)
          acc[i][j] = __builtin_amdgcn_mfma_f32_16x16x32_bf16(af[i], bf_[j], acc[i][j], 0, 0, 0);
    }
    __syncthreads();
  }
#pragma unroll
  for (int i = 0; i < 4; ++i) {
    int mrow = m0 + wr * 64 + i * 16 + ((l >> 4) << 2);
#pragma unroll
    for (int j = 0; j < 4; ++j) {
      int ncol = n0 + wc * 64 + j * 16 + (l & 15);
      float* cp = C + (size_t)mrow * N + ncol;
#pragma unroll
      for (int r = 0; r < 4; ++r) cp[(size_t)r * N] = acc[i][j][r];
    }
  }
}

// ---------------- fused gmax + conv-bias + relu + pairwise maxpool + transpose ----------------
__global__ __launch_bounds__(256) void k_gfinal(const float* __restrict__ mlpout,
                                                const float* __restrict__ mlp_b,
                                                const int* __restrict__ idxo,
                                                const float* __restrict__ wo,
                                                const float* __restrict__ convb,
                                                const float* __restrict__ cb,
                                                float* __restrict__ out) {
  __shared__ float tile[32][33];
  __shared__ int sj[64][KNB];
  __shared__ float sw[64][KNB];
  int b = blockIdx.z, c0 = blockIdx.y * 32, t20 = blockIdx.x * 32;
  int tid = threadIdx.x;
  int nbase = b * T_DIM + t20 * 2;
  for (int e = tid; e < 64 * KNB; e += 256) {
    int ln = e / KNB, k = e - ln * KNB;
    sj[ln][k] = b * T_DIM + idxo[(size_t)(nbase + ln) * KNB + k];
    sw[ln][k] = wo[(size_t)(nbase + ln) * KNB + k];
  }
  __syncthreads();
  int tx = tid & 31, ty = tid >> 5;
  int c = c0 + tx;
  float bias_c = cb[c];
  float mbias = mlp_b[c];
#pragma unroll
  for (int rr = 0; rr < 4; ++rr) {
    int lt2 = ty + 8 * rr;
    float res[2];
#pragma unroll
    for (int s = 0; s < 2; ++s) {
      int ln = 2 * lt2 + s;
      int n = nbase + ln;
      float q = mlpout[(size_t)n * 512 + 256 + c] + mbias;
      float mx = -3.4e38f;
#pragma unroll
      for (int k = 0; k < KNB; ++k) {
        float v = (mlpout[(size_t)sj[ln][k] * 512 + c] + q) * sw[ln][k];
        mx = fmaxf(mx, v);
      }
      float v = convb[(size_t)n * C_DIM + c] + mx + bias_c;
      res[s] = fmaxf(v, 0.f);
    }
    tile[lt2][tx] = fmaxf(res[0], res[1]);
  }
  __syncthreads();
#pragma unroll
  for (int rr = 0; rr < 4; ++rr) {
    int cc = c0 + ty + 8 * rr;
    out[((size_t)b * C_DIM + cc) * (T_DIM / 2) + t20 + tx] = tile[tx][ty + 8 * rr];
  }
}

// ---------------- merged repack + fixcount zeroing ----------------
__global__ void k_repack(const float* __restrict__ cw, const float* __restrict__ mw,
                         __bf16* __restrict__ wk3, __bf16* __restrict__ mlpB,
                         __bf16* __restrict__ zp, int* __restrict__ fixcount) {
  int i = blockIdx.x * 256 + threadIdx.x;
  if (i == 0) fixcount[0] = 0;
  if (i < 3 * C_DIM * C_DIM) {
    int o = i / 768;
    int rem = i - o * 768;
    int tap = rem >> 8;
    int ii = rem & 255;
    wk3[i] = bfbits(f2bf_rn(cw[(size_t)o * 768 + ii * 3 + tap]));
  } else {
    int m = i - 3 * C_DIM * C_DIM;
    if (m < 512 * 256) {
      int r = m >> 8;
      int col = m & 255;
      mlpB[m] = bfbits(f2bf_rn(mw[(size_t)(r & 255) * 512 + ((r >> 8) << 8) + col]));
    }
  }
  if (blockIdx.x == 0 && threadIdx.x < 128) zp[threadIdx.x] = bfbits(0);
}

extern "C" void kernel_launch(void* const* d_in, const int* in_sizes, int n_in,
                              void* d_out, int out_size, void* d_ws, size_t ws_size,
                              hipStream_t stream) {
  const float* x = (const float*)d_in[0];
  const float* conv_w = (const float*)d_in[2];
  const float* conv_b = (const float*)d_in[3];
  const float* mlp_w = (const float*)d_in[4];
  const float* mlp_b = (const float*)d_in[5];
  float* out = (float*)d_out;

  char* ws = (char*)d_ws;
  size_t off = 0;
  auto alloc = [&](size_t bytes) -> void* {
    void* p = ws + off;
    off += (bytes + 255) & ~(size_t)255;
    return p;
  };
  __bf16* Fh = (__bf16*)alloc((size_t)NPTS * C_DIM * 2);
  __bf16* Fl = (__bf16*)alloc((size_t)NPTS * C_DIM * 2);
  float* convout = (float*)alloc((size_t)NPTS * C_DIM * 4);
  float* mlpout = (float*)alloc((size_t)NPTS * 512 * 4);
  float* sq = (float*)alloc((size_t)NPTS * 4);
  int* idxb = (int*)alloc((size_t)NPTS * KNB * 4);
  float* wb = (float*)alloc((size_t)NPTS * KNB * 4);
  int* fixlist = (int*)alloc((size_t)NPTS * 4);
  int* fixcount = (int*)alloc(256);
  u64* kbuf = (u64*)alloc((size_t)BS * NCH * T_DIM * 12 * 8);  // 25.2 MB
  u64* bbuf = (u64*)alloc((size_t)BS * NCH * T_DIM * 8);       // 2.1 MB
  u64* kpart = (u64*)alloc((size_t)NPTS * 32 * KNB * 8);       // 41.9 MB
  __bf16* wk3 = (__bf16*)alloc((size_t)3 * C_DIM * C_DIM * 2);
  __bf16* mlpB = (__bf16*)alloc((size_t)512 * 256 * 2);
  __bf16* zp = (__bf16*)alloc(512);

  k_repack<<<dim3(1280), 256, 0, stream>>>(conv_w, mlp_w, wk3, mlpB, zp, fixcount);
  k_transpose_split<<<dim3(T_DIM / 32, C_DIM / 32, BS), 256, 0, stream>>>(x, Fh, Fl);
  k_sq<<<dim3(NPTS / 4), 256, 0, stream>>>(Fh, Fl, sq);

  // gram tile + per-lane min-4 reduce (4096 blocks), then merge, then rare fix
  k_gram_reduce<<<dim3(NCH, T_DIM / 64, BS), 256, 0, stream>>>(Fh, Fl, sq, kbuf, bbuf);
  k_topk_merge<<<dim3(T_DIM / 4, BS), 256, 0, stream>>>(kbuf, bbuf, sq, idxb, wb, fixlist, fixcount);
  k_fix_dots<<<dim3(32, 64), 256, 0, stream>>>(Fh, Fl, sq, fixlist, fixcount, kpart);
  k_fix_merge<<<dim3(64), 256, 0, stream>>>(sq, fixlist, fixcount, kpart, idxb, wb);

  k_gemm_fused<<<dim3(6, NPTS / 128), 256, 0, stream>>>(Fh, mlpB, wk3, mlpout, convout, zp);

  k_gfinal<<<dim3((T_DIM / 2) / 32, C_DIM / 32, BS), 256, 0, stream>>>(
      mlpout, mlp_b, idxb, wb, convout, conv_b, out);
}